// Round 4
// baseline (11675.494 us; speedup 1.0000x reference)
//
#include <hip/hip_runtime.h>
#include <hip/hip_bf16.h>

// ---------------------------------------------------------------------------
// CTM round 3: persistent tick-loop kernel with SOFTWARE grid barrier
// (regular launch, 256 blocks — one per CU guarantees co-residency),
// replacing the failed hipLaunchCooperativeKernel path.
// ---------------------------------------------------------------------------

#define B_ 64
#define S_ 512
#define F_ 1024
#define DMODEL 2048
#define DMEM 32
#define DIN 1024
#define NH 16
#define DH 64
#define DOUT 1000
#define NSYNC 512
#define TICKS 16
#define HNLM 32
#define HIST_W 48
#define GPERS 256  // persistent grid size (<= 1 block/CU -> co-resident)

typedef __attribute__((ext_vector_type(8))) short short8;
typedef __attribute__((ext_vector_type(4))) float f32x4;

__device__ inline void store_f(float* p, float v) { *p = v; }
__device__ inline void store_f(__hip_bfloat16* p, float v) { *p = __float2bfloat16(v); }

__device__ inline short f2bs(float f) {
  __hip_bfloat16 h = __float2bfloat16(f);
  return *reinterpret_cast<short*>(&h);
}

__device__ inline float gelu_f(float x) {
  float x3 = x * x * x;
  return 0.5f * x * (1.f + tanhf(0.7978845608028654f * (x + 0.044715f * x3)));
}

__device__ inline float bf_lo(unsigned v) { return __uint_as_float(v << 16); }
__device__ inline float bf_hi(unsigned v) { return __uint_as_float(v & 0xffff0000u); }

// ---------------- software grid barrier (one counter per instance) ----------
__device__ __forceinline__ void gbar(int* cnt, int idx) {
  __syncthreads();
  if (threadIdx.x == 0) {
    __threadfence();
    __hip_atomic_fetch_add(&cnt[idx], 1, __ATOMIC_ACQ_REL, __HIP_MEMORY_SCOPE_AGENT);
    while (__hip_atomic_load(&cnt[idx], __ATOMIC_ACQUIRE, __HIP_MEMORY_SCOPE_AGENT) < GPERS) {
      __builtin_amdgcn_s_sleep(2);
    }
    __threadfence();
  }
  __syncthreads();
}

// ---------------- weight prep ----------------
__global__ __launch_bounds__(256) void transpose_bf16_kernel(const float* __restrict__ W,
                                                             __hip_bfloat16* __restrict__ Wt,
                                                             int K, int N, int Npad) {
  __shared__ float t[32][33];
  const int tx = threadIdx.x, ty = threadIdx.y;  // 32 x 8
  const int n0 = blockIdx.x * 32, k0 = blockIdx.y * 32;
#pragma unroll
  for (int i = 0; i < 4; i++) {
    int k = k0 + ty + i * 8;
    t[ty + i * 8][tx] = (k < K && n0 + tx < N) ? W[(size_t)k * N + n0 + tx] : 0.f;
  }
  __syncthreads();
#pragma unroll
  for (int i = 0; i < 4; i++) {
    int n = n0 + ty + i * 8;
    if (n < Npad && k0 + tx < K)
      Wt[(size_t)n * K + k0 + tx] = __float2bfloat16(t[tx][ty + i * 8]);
  }
}

__global__ void conv_bf16_kernel(const float* __restrict__ src, __hip_bfloat16* __restrict__ dst,
                                 int n) {
  int i = blockIdx.x * 256 + threadIdx.x;
  if (i < n) dst[i] = __float2bfloat16(src[i]);
}

__global__ void bqaq_kernel(const float* __restrict__ b_q, const float* __restrict__ b_aq,
                            const __hip_bfloat16* __restrict__ Wt_aq, float* __restrict__ b_qaq) {
  int n = blockIdx.x * 256 + threadIdx.x;
  if (n >= DIN) return;
  const __hip_bfloat16* wr = Wt_aq + (size_t)n * DIN;
  float s = b_aq[n];
  for (int k = 0; k < DIN; k++) s += b_q[k] * __bfloat162float(wr[k]);
  b_qaq[n] = s;
}

// ---------------- big MFMA GEMM (precompute) ----------------
__device__ inline short8 load_chunk(const __hip_bfloat16* p) {
  return *reinterpret_cast<const short8*>(p);
}
__device__ inline short8 load_chunk(const float* p) {
  short8 r;
#pragma unroll
  for (int j = 0; j < 8; j++) r[j] = f2bs(p[j]);
  return r;
}

template <int TRANSC, typename TA, typename TC>
__global__ __launch_bounds__(256) void gemm_big(const TA* __restrict__ A,
                                                const __hip_bfloat16* __restrict__ Bt,
                                                const float* __restrict__ bias,
                                                TC* __restrict__ C, int M, int N, int K) {
  __shared__ short lsA[128 * 64];
  __shared__ short lsB[128 * 64];
  const int tid = threadIdx.x;
  const int l = tid & 63, w = tid >> 6;
  const int wr = (w >> 1) * 64, wc = (w & 1) * 64;
  const int brow = blockIdx.y * 128, bcol = blockIdx.x * 128;
  f32x4 acc[4][4];
#pragma unroll
  for (int i = 0; i < 4; i++)
#pragma unroll
    for (int j = 0; j < 4; j++)
#pragma unroll
      for (int r = 0; r < 4; r++) acc[i][j][r] = 0.f;

  short8 ra[4], rb[4];
  auto gload = [&](int k0) {
#pragma unroll
    for (int q = 0; q < 4; q++) {
      int i = tid + q * 256;
      int row = i >> 3, c = i & 7;
      ra[q] = load_chunk(A + (size_t)(brow + row) * K + k0 + c * 8);
      rb[q] = load_chunk(Bt + (size_t)(bcol + row) * K + k0 + c * 8);
    }
  };
  auto lwrite = [&]() {
#pragma unroll
    for (int q = 0; q < 4; q++) {
      int i = tid + q * 256;
      int row = i >> 3, c = i & 7;
      int sw = c ^ (row & 7);
      *reinterpret_cast<short8*>(&lsA[row * 64 + sw * 8]) = ra[q];
      *reinterpret_cast<short8*>(&lsB[row * 64 + sw * 8]) = rb[q];
    }
  };
  gload(0);
  for (int k0 = 0; k0 < K; k0 += 64) {
    __syncthreads();
    lwrite();
    if (k0 + 64 < K) gload(k0 + 64);
    __syncthreads();
#pragma unroll
    for (int ks = 0; ks < 2; ks++) {
      short8 af[4], bfv[4];
#pragma unroll
      for (int mi = 0; mi < 4; mi++) {
        int row = wr + mi * 16 + (l & 15);
        int c = ks * 4 + (l >> 4);
        af[mi] = *reinterpret_cast<const short8*>(&lsA[row * 64 + (c ^ (row & 7)) * 8]);
      }
#pragma unroll
      for (int ni = 0; ni < 4; ni++) {
        int row = wc + ni * 16 + (l & 15);
        int c = ks * 4 + (l >> 4);
        bfv[ni] = *reinterpret_cast<const short8*>(&lsB[row * 64 + (c ^ (row & 7)) * 8]);
      }
#pragma unroll
      for (int mi = 0; mi < 4; mi++)
#pragma unroll
        for (int ni = 0; ni < 4; ni++)
          acc[mi][ni] =
              __builtin_amdgcn_mfma_f32_16x16x32_bf16(af[mi], bfv[ni], acc[mi][ni], 0, 0, 0);
    }
  }
#pragma unroll
  for (int mi = 0; mi < 4; mi++)
#pragma unroll
    for (int ni = 0; ni < 4; ni++)
#pragma unroll
      for (int r = 0; r < 4; r++) {
        int row = brow + wr + mi * 16 + (l >> 4) * 4 + r;
        int col = bcol + wc + ni * 16 + (l & 15);
        float v = acc[mi][ni][r];
        if (bias) v += bias[col];
        if (TRANSC)
          store_f(&C[(size_t)col * M + row], v);
        else
          store_f(&C[(size_t)row * N + col], v);
      }
}

// ---------------- LayerNorm (precompute: kv) ----------------
template <typename TOUT>
__global__ __launch_bounds__(256) void ln_kernel(const float* __restrict__ x,
                                                 const float* __restrict__ g,
                                                 const float* __restrict__ be,
                                                 TOUT* __restrict__ out, int C,
                                                 size_t row_stride, int col_stride) {
  const int row = blockIdx.x;
  const int tid = threadIdx.x;
  const float* xr = x + (size_t)row * C;
  float s = 0.f, s2 = 0.f;
  for (int c = tid; c < C; c += 256) {
    float v = xr[c];
    s += v;
    s2 += v * v;
  }
  __shared__ float r1[256], r2[256];
  r1[tid] = s;
  r2[tid] = s2;
  __syncthreads();
  for (int st = 128; st > 0; st >>= 1) {
    if (tid < st) {
      r1[tid] += r1[tid + st];
      r2[tid] += r2[tid + st];
    }
    __syncthreads();
  }
  float mean = r1[0] / C;
  float var = r2[0] / C - mean * mean;
  float inv = 1.0f / sqrtf(var + 1e-5f);
  for (int c = tid; c < C; c += 256) {
    float v = (xr[c] - mean) * inv * g[c] + be[c];
    store_f(&out[(size_t)row * row_stride + (size_t)c * col_stride], v);
  }
}

// ---------------- init kernels ----------------
__global__ void init_act_kernel(const float* __restrict__ init_state, float* __restrict__ act) {
  int i = blockIdx.x * 256 + threadIdx.x;
  if (i < B_ * DMODEL) act[i] = init_state[i & (DMODEL - 1)];
}

__global__ void init_hist_kernel(const float* __restrict__ init_hist, float* __restrict__ hist) {
  int i = blockIdx.x * 256 + threadIdx.x;
  if (i >= B_ * DMODEL * DMEM) return;
  int m = i & (DMEM - 1);
  int bd = i >> 5;
  int d = bd & (DMODEL - 1);
  hist[(size_t)bd * HIST_W + m] = init_hist[d * DMEM + m];
}

// also precomputes rA/rO and tick-0 action-sync state
__global__ void init_sync_kernel(const float* __restrict__ init_state,
                                 const float* __restrict__ decay_action,
                                 const float* __restrict__ decay_out,
                                 const int* __restrict__ la, const int* __restrict__ ra,
                                 const int* __restrict__ lo, const int* __restrict__ ro,
                                 float* __restrict__ aA, float* __restrict__ bA,
                                 float* __restrict__ aO, float* __restrict__ bO,
                                 __hip_bfloat16* __restrict__ syncA, float* __restrict__ rAv,
                                 float* __restrict__ rOv) {
  int i = blockIdx.x * 256 + threadIdx.x;
  if (i >= B_ * NSYNC) return;
  int j = i & (NSYNC - 1);
  if (i < NSYNC) {
    rAv[i] = expf(-fminf(fmaxf(decay_action[i], 0.f), 15.f));
    rOv[i] = expf(-fminf(fmaxf(decay_out[i], 0.f), 15.f));
  }
  float pA = init_state[la[j]] * init_state[ra[j]];
  aA[i] = pA;
  bA[i] = 1.f;
  syncA[i] = __float2bfloat16(pA);  // pA / sqrt(1)
  aO[i] = init_state[lo[j]] * init_state[ro[j]];
  bO[i] = 1.f;
}

// ---------------- persistent tick kernel ----------------
struct CArgs {
  const __hip_bfloat16 *Wt_qaq, *Wt_ao, *Wt_s1, *Wt_s2, *Wt_out;
  const __hip_bfloat16 *kh, *vh;
  const float *b_qaq, *b_ao, *b_s1, *b_s2, *b_out;
  const float *g_s, *be_s, *g_n, *be_n;
  const float *W_n1, *b_n1, *W_n2, *b_n2;
  const int *la, *ra, *lo, *ro;
  const float *rAv, *rOv;
  float *qhb, *part, *histf, *act, *aA, *bA, *aO, *bO, *nlmraw, *outp;
  __hip_bfloat16 *syncA, *syncO, *attnv, *pre, *h1;
  int* bar;
};

// one 64xN-tile MFMA matmul step: C-tile rows 0..63, cols [bcol,bcol+64), K in [kb,kb+kchunk)
template <typename EPI>
__device__ __forceinline__ void mm_tile64(const __hip_bfloat16* __restrict__ A, int lda,
                                          const __hip_bfloat16* __restrict__ Bt, int ldb,
                                          int bcol, int kb, int kchunk, short* lsA, short* lsB,
                                          EPI epi) {
  const int tid = threadIdx.x;
  const int l = tid & 63, w = tid >> 6;
  f32x4 acc[4];
#pragma unroll
  for (int i = 0; i < 4; i++)
#pragma unroll
    for (int r = 0; r < 4; r++) acc[i][r] = 0.f;
  short8 ra[2], rb[2];
  auto gload = [&](int k0) {
#pragma unroll
    for (int q = 0; q < 2; q++) {
      int i = tid + q * 256;
      int row = i >> 3, c = i & 7;
      ra[q] = *reinterpret_cast<const short8*>(A + (size_t)row * lda + k0 + c * 8);
      rb[q] = *reinterpret_cast<const short8*>(Bt + (size_t)(bcol + row) * ldb + k0 + c * 8);
    }
  };
  auto lwrite = [&]() {
#pragma unroll
    for (int q = 0; q < 2; q++) {
      int i = tid + q * 256;
      int row = i >> 3, c = i & 7;
      int sw = c ^ (row & 7);
      *reinterpret_cast<short8*>(&lsA[row * 64 + sw * 8]) = ra[q];
      *reinterpret_cast<short8*>(&lsB[row * 64 + sw * 8]) = rb[q];
    }
  };
  gload(kb);
  for (int k0 = kb; k0 < kb + kchunk; k0 += 64) {
    __syncthreads();
    lwrite();
    if (k0 + 64 < kb + kchunk) gload(k0 + 64);
    __syncthreads();
#pragma unroll
    for (int ks = 0; ks < 2; ks++) {
      int rowa = w * 16 + (l & 15);
      int c = ks * 4 + (l >> 4);
      short8 af = *reinterpret_cast<const short8*>(&lsA[rowa * 64 + (c ^ (rowa & 7)) * 8]);
#pragma unroll
      for (int ni = 0; ni < 4; ni++) {
        int rowb = ni * 16 + (l & 15);
        short8 bfv = *reinterpret_cast<const short8*>(&lsB[rowb * 64 + (c ^ (rowb & 7)) * 8]);
        acc[ni] = __builtin_amdgcn_mfma_f32_16x16x32_bf16(af, bfv, acc[ni], 0, 0, 0);
      }
    }
  }
#pragma unroll
  for (int ni = 0; ni < 4; ni++)
#pragma unroll
    for (int r = 0; r < 4; r++) {
      int m = w * 16 + (l >> 4) * 4 + r;
      int n = bcol + ni * 16 + (l & 15);
      epi(m, n, acc[ni][r]);
    }
}

__global__ __launch_bounds__(256) void ctm_coop(CArgs a) {
  __shared__ __align__(16) char smem[17408];
  short* lsA = (short*)smem;
  short* lsB = (short*)(smem + 8192);
  float* sf = (float*)smem;
  const int tid = threadIdx.x;
  const int gbx = blockIdx.x;
  const int G = GPERS;
  int bi = 0;  // barrier instance index (same sequence on all blocks)

  for (int t = 0; t < TICKS; ++t) {
    // ---- P1: qh = syncA @ (W_q W_aq) + b_qaq ; pack act -> pre[:,1024:] ----
    for (int u = gbx; u < 16; u += G)
      mm_tile64(a.syncA, NSYNC, a.Wt_qaq, NSYNC, u * 64, 0, NSYNC, lsA, lsB,
                [&](int m, int n, float v) { a.qhb[m * DIN + n] = v + a.b_qaq[n]; });
    if (gbx >= 16) {
      int stride = (G - 16) * 256;
      for (int i = (gbx - 16) * 256 + tid; i < B_ * DMODEL; i += stride) {
        int b = i >> 11, j = i & (DMODEL - 1);
        a.pre[(size_t)b * 3072 + DIN + j] = __float2bfloat16(a.act[i]);
      }
    }
    gbar(a.bar, bi++);
    // ---- P2: attention ----
    for (int u = gbx; u < B_ * NH; u += G) {
      const int b = u >> 4, h = u & (NH - 1);
      float* qs = sf;
      float* wv = sf + 64;
      float* red = sf + 576;
      if (tid < DH) qs[tid] = a.qhb[b * DIN + h * DH + tid];
      __syncthreads();
      float sc[2];
#pragma unroll
      for (int r = 0; r < 2; ++r) {
        int s = tid + r * 256;
        const unsigned* kp =
            reinterpret_cast<const unsigned*>(a.kh + ((size_t)(b * S_ + s) * DIN + h * DH));
        float accv = 0.f;
#pragma unroll
        for (int q = 0; q < DH / 2; ++q) {
          unsigned uu = kp[q];
          accv += qs[q * 2 + 0] * bf_lo(uu) + qs[q * 2 + 1] * bf_hi(uu);
        }
        sc[r] = accv * 0.125f;
      }
      red[tid] = fmaxf(sc[0], sc[1]);
      __syncthreads();
      for (int st = 128; st > 0; st >>= 1) {
        if (tid < st) red[tid] = fmaxf(red[tid], red[tid + st]);
        __syncthreads();
      }
      const float mx = red[0];
      __syncthreads();
      float e0 = expf(sc[0] - mx), e1 = expf(sc[1] - mx);
      wv[tid] = e0;
      wv[tid + 256] = e1;
      red[tid] = e0 + e1;
      __syncthreads();
      for (int st = 128; st > 0; st >>= 1) {
        if (tid < st) red[tid] += red[tid + st];
        __syncthreads();
      }
      const float invZ = 1.f / red[0];
      __syncthreads();
      const int d = tid & 63, g2 = tid >> 6;
      const __hip_bfloat16* vp = a.vh + ((size_t)b * S_ * DIN + (size_t)h * DH + d);
      float accv = 0.f;
      for (int s = g2; s < S_; s += 4) accv += wv[s] * __bfloat162float(vp[(size_t)s * DIN]);
      red[tid] = accv;
      __syncthreads();
      if (tid < 64) {
        float r = red[tid] + red[64 + tid] + red[128 + tid] + red[192 + tid];
        a.attnv[b * DIN + h * DH + tid] = __float2bfloat16(r * invZ);
      }
      __syncthreads();
    }
    gbar(a.bar, bi++);
    // ---- P3: ao GEMM -> pre[:, :1024] ----
    for (int u = gbx; u < 16; u += G)
      mm_tile64(a.attnv, DIN, a.Wt_ao, DIN, u * 64, 0, DIN, lsA, lsB, [&](int m, int n, float v) {
        a.pre[(size_t)m * 3072 + n] = __float2bfloat16(v + a.b_ao[n]);
      });
    gbar(a.bar, bi++);
    // ---- P4: s1 GEMM split-K8 ----
    for (int u = gbx; u < 256; u += G) {
      int nt = u & 31, ks = u >> 5;
      mm_tile64(a.pre, 3072, a.Wt_s1, 3072, nt * 64, ks * 384, 384, lsA, lsB,
                [&](int m, int n, float v) { a.part[((size_t)ks * 64 + m) * DMODEL + n] = v; });
    }
    gbar(a.bar, bi++);
    // ---- P5: s1 reduce + gelu -> h1 ----
    for (int u = gbx; u < 64; u += G) {
      for (int i = 0; i < 8; i++) {
        int n = tid + i * 256;
        float s = a.b_s1[n];
        for (int ks = 0; ks < 8; ks++) s += a.part[((size_t)ks * 64 + u) * DMODEL + n];
        a.h1[(size_t)u * DMODEL + n] = __float2bfloat16(gelu_f(s));
      }
    }
    gbar(a.bar, bi++);
    // ---- P6: s2 GEMM split-K8 ----
    for (int u = gbx; u < 256; u += G) {
      int nt = u & 31, ks = u >> 5;
      mm_tile64(a.h1, DMODEL, a.Wt_s2, DMODEL, nt * 64, ks * 256, 256, lsA, lsB,
                [&](int m, int n, float v) { a.part[((size_t)ks * 64 + m) * DMODEL + n] = v; });
    }
    gbar(a.bar, bi++);
    // ---- P7: s2 reduce + LN -> hist slot 32+t ----
    for (int u = gbx; u < 64; u += G) {
      float v[8];
      float s = 0.f, s2 = 0.f;
      for (int i = 0; i < 8; i++) {
        int n = tid + i * 256;
        float x = a.b_s2[n];
        for (int ks = 0; ks < 8; ks++) x += a.part[((size_t)ks * 64 + u) * DMODEL + n];
        v[i] = x;
        s += x;
        s2 += x * x;
      }
      float* r1 = sf;
      float* r2 = sf + 256;
      r1[tid] = s;
      r2[tid] = s2;
      __syncthreads();
      for (int st = 128; st > 0; st >>= 1) {
        if (tid < st) {
          r1[tid] += r1[tid + st];
          r2[tid] += r2[tid + st];
        }
        __syncthreads();
      }
      float mean = r1[0] / DMODEL;
      float var = r2[0] / DMODEL - mean * mean;
      float inv = 1.f / sqrtf(var + 1e-5f);
      __syncthreads();
      for (int i = 0; i < 8; i++) {
        int n = tid + i * 256;
        float pa = (v[i] - mean) * inv * a.g_s[n] + a.be_s[n];
        a.histf[((size_t)u * DMODEL + n) * HIST_W + 32 + t] = pa;
      }
      __syncthreads();
    }
    gbar(a.bar, bi++);
    // ---- P8: NLM ----
    for (int u = gbx; u < 512; u += G) {
      float* w1s = sf;         // 4096 f
      float* b1s = sf + 4096;  // 128 f
      int d0 = u * 4;
      for (int i = tid; i < 4096; i += 256) w1s[i] = a.W_n1[(size_t)d0 * 1024 + i];
      if (tid < 128) b1s[tid] = a.b_n1[d0 * 32 + tid];
      __syncthreads();
      int b = tid & 63, dsub = tid >> 6;
      int d = d0 + dsub;
      const float* hw = a.histf + ((size_t)(b * DMODEL + d)) * HIST_W + t + 1;
      float win[DMEM];
#pragma unroll
      for (int m = 0; m < DMEM; ++m) win[m] = hw[m];
      const float* w1 = w1s + dsub * 1024;
      const float* bb = b1s + dsub * 32;
      const float* w2 = a.W_n2 + d * HNLM;
      float acc = 0.f;
      for (int h = 0; h < HNLM; ++h) {
        float s = bb[h];
#pragma unroll
        for (int m = 0; m < DMEM; ++m) s += win[m] * w1[m * HNLM + h];
        acc += fmaxf(s, 0.f) * w2[h];
      }
      a.nlmraw[(size_t)b * DMODEL + d] = acc + a.b_n2[d];
      __syncthreads();
    }
    gbar(a.bar, bi++);
    // ---- P9: LN(nlmraw) -> act ; syncA(t+1), syncO(t) ----
    for (int u = gbx; u < 64; u += G) {
      const float* xr = a.nlmraw + (size_t)u * DMODEL;
      float* arow = sf;         // 2048 f
      float* r1 = sf + 2048;    // 256 f
      float* r2 = sf + 2304;    // 256 f
      float xv[8];
      float s = 0.f, s2 = 0.f;
      for (int i = 0; i < 8; i++) {
        float x = xr[tid + i * 256];
        xv[i] = x;
        s += x;
        s2 += x * x;
      }
      r1[tid] = s;
      r2[tid] = s2;
      __syncthreads();
      for (int st = 128; st > 0; st >>= 1) {
        if (tid < st) {
          r1[tid] += r1[tid + st];
          r2[tid] += r2[tid + st];
        }
        __syncthreads();
      }
      float mean = r1[0] / DMODEL;
      float var = r2[0] / DMODEL - mean * mean;
      float inv = 1.f / sqrtf(var + 1e-5f);
      __syncthreads();
      for (int i = 0; i < 8; i++) {
        int n = tid + i * 256;
        float av = (xv[i] - mean) * inv * a.g_n[n] + a.be_n[n];
        a.act[(size_t)u * DMODEL + n] = av;
        arow[n] = av;
      }
      __syncthreads();
      for (int j = tid; j < NSYNC; j += 256) {
        size_t idx = (size_t)u * NSYNC + j;
        float pA = arow[a.la[j]] * arow[a.ra[j]];
        float r = a.rAv[j];
        float av2 = r * a.aA[idx] + pA, bv2 = r * a.bA[idx] + 1.f;
        a.aA[idx] = av2;
        a.bA[idx] = bv2;
        a.syncA[idx] = __float2bfloat16(av2 / sqrtf(bv2));
        float pO = arow[a.lo[j]] * arow[a.ro[j]];
        float ro = a.rOv[j];
        av2 = ro * a.aO[idx] + pO;
        bv2 = ro * a.bO[idx] + 1.f;
        a.aO[idx] = av2;
        a.bO[idx] = bv2;
        a.syncO[idx] = __float2bfloat16(av2 / sqrtf(bv2));
      }
      __syncthreads();
    }
    gbar(a.bar, bi++);
    // ---- P10: output head (GEMV + entropy); no trailing barrier needed ----
    for (int u = gbx; u < 64; u += G) {
      float* so = sf;          // 512 f
      float* pv = sf + 512;    // 1024 f
      float* red = sf + 1536;  // 256 f
      so[tid] = __bfloat162float(a.syncO[(size_t)u * NSYNC + tid]);
      so[tid + 256] = __bfloat162float(a.syncO[(size_t)u * NSYNC + 256 + tid]);
      __syncthreads();
      float pr[4];
#pragma unroll
      for (int i = 0; i < 4; i++) {
        int n = tid + i * 256;
        pr[i] = 0.f;
        if (n < DOUT) {
          const unsigned* wr = reinterpret_cast<const unsigned*>(a.Wt_out + (size_t)n * NSYNC);
          float sacc = a.b_out[n];
          for (int c = 0; c < 256; c++) {
            unsigned uu = wr[c];
            sacc += so[2 * c] * bf_lo(uu) + so[2 * c + 1] * bf_hi(uu);
          }
          pr[i] = sacc;
          pv[n] = sacc;
        }
      }
      __syncthreads();
      float m = -1e30f;
      for (int o = tid; o < DOUT; o += 256) m = fmaxf(m, pv[o]);
      red[tid] = m;
      __syncthreads();
      for (int st = 128; st > 0; st >>= 1) {
        if (tid < st) red[tid] = fmaxf(red[tid], red[tid + st]);
        __syncthreads();
      }
      m = red[0];
      __syncthreads();
      float z = 0.f, s1 = 0.f;
      for (int o = tid; o < DOUT; o += 256) {
        float wv2 = pv[o] - m;
        float e = expf(wv2);
        z += e;
        s1 += e * wv2;
      }
      red[tid] = z;
      __syncthreads();
      for (int st = 128; st > 0; st >>= 1) {
        if (tid < st) red[tid] += red[tid + st];
        __syncthreads();
      }
      const float Z = red[0];
      __syncthreads();
      red[tid] = s1;
      __syncthreads();
      for (int st = 128; st > 0; st >>= 1) {
        if (tid < st) red[tid] += red[tid + st];
        __syncthreads();
      }
      const float S1 = red[0];
      const float ne = -(S1 / Z - logf(Z)) / 6.907755278982137f;
#pragma unroll
      for (int i = 0; i < 4; i++) {
        int n = tid + i * 256;
        if (n < DOUT) a.outp[((size_t)u * DOUT + n) * TICKS + t] = pr[i];
      }
      if (tid == 0) {
        float* c = a.outp + (size_t)B_ * DOUT * TICKS;
        c[u * 2 * TICKS + t] = ne;
        c[u * 2 * TICKS + TICKS + t] = 1.f - ne;
      }
      __syncthreads();
    }
  }
}

// ---------------------------------------------------------------------------
extern "C" void kernel_launch(void* const* d_in, const int* in_sizes, int n_in,
                              void* d_out, int out_size, void* d_ws, size_t ws_size,
                              hipStream_t stream) {
  const float* x = (const float*)d_in[0];
  const float* W_kv = (const float*)d_in[1];
  const float* b_kv = (const float*)d_in[2];
  const float* g_kv = (const float*)d_in[3];
  const float* be_kv = (const float*)d_in[4];
  const float* W_q = (const float*)d_in[5];
  const float* b_q = (const float*)d_in[6];
  const float* W_aq = (const float*)d_in[7];
  const float* b_aq = (const float*)d_in[8];
  const float* W_ak = (const float*)d_in[9];
  const float* b_ak = (const float*)d_in[10];
  const float* W_av = (const float*)d_in[11];
  const float* b_av = (const float*)d_in[12];
  const float* W_ao = (const float*)d_in[13];
  const float* b_ao = (const float*)d_in[14];
  const float* W_s1 = (const float*)d_in[15];
  const float* b_s1 = (const float*)d_in[16];
  const float* W_s2 = (const float*)d_in[17];
  const float* b_s2 = (const float*)d_in[18];
  const float* g_s = (const float*)d_in[19];
  const float* be_s = (const float*)d_in[20];
  const float* W_n1 = (const float*)d_in[21];
  const float* b_n1 = (const float*)d_in[22];
  const float* W_n2 = (const float*)d_in[23];
  const float* b_n2 = (const float*)d_in[24];
  const float* g_n = (const float*)d_in[25];
  const float* be_n = (const float*)d_in[26];
  const float* init_state = (const float*)d_in[27];
  const float* init_hist = (const float*)d_in[28];
  const float* decay_action = (const float*)d_in[29];
  const float* decay_out = (const float*)d_in[30];
  const float* W_out = (const float*)d_in[31];
  const float* b_out = (const float*)d_in[32];
  const int* idx_la = (const int*)d_in[33];
  const int* idx_ra = (const int*)d_in[34];
  const int* idx_lo = (const int*)d_in[35];
  const int* idx_ro = (const int*)d_in[36];
  float* out = (float*)d_out;

  // ---- workspace carve ----
  char* wsb = (char*)d_ws;
  size_t off = 0;
  auto alloc = [&](size_t bytes) -> char* {
    char* p = wsb + off;
    off += (bytes + 255) & ~(size_t)255;
    return p;
  };
  const size_t MS = (size_t)B_ * S_;  // 32768
  char* regionA = alloc(MS * DIN * 4);  // kvraw fp32; later kh+vh bf16
  __hip_bfloat16* kv = (__hip_bfloat16*)alloc(MS * DIN * 2);
  float* histf = (float*)alloc((size_t)B_ * DMODEL * HIST_W * 4);
  __hip_bfloat16* Wt_kv = (__hip_bfloat16*)alloc((size_t)DIN * F_ * 2);
  __hip_bfloat16* Wt_ak = (__hip_bfloat16*)alloc((size_t)DIN * DIN * 2);
  __hip_bfloat16* Wt_av = (__hip_bfloat16*)alloc((size_t)DIN * DIN * 2);
  __hip_bfloat16* Wt_aq = (__hip_bfloat16*)alloc((size_t)DIN * DIN * 2);
  __hip_bfloat16* Wt_ao = (__hip_bfloat16*)alloc((size_t)DIN * DIN * 2);
  __hip_bfloat16* W_qb = (__hip_bfloat16*)alloc((size_t)NSYNC * DIN * 2);
  __hip_bfloat16* Wt_qaq = (__hip_bfloat16*)alloc((size_t)DIN * NSYNC * 2);
  __hip_bfloat16* Wt_s1 = (__hip_bfloat16*)alloc((size_t)DMODEL * (DIN + DMODEL) * 2);
  __hip_bfloat16* Wt_s2 = (__hip_bfloat16*)alloc((size_t)DMODEL * DMODEL * 2);
  __hip_bfloat16* Wt_out = (__hip_bfloat16*)alloc((size_t)DOUT * NSYNC * 2);
  float* b_qaq = (float*)alloc(DIN * 4);
  float* partial = (float*)alloc((size_t)8 * 64 * DMODEL * 4);
  float* act = (float*)alloc((size_t)B_ * DMODEL * 4);
  float* aA = (float*)alloc((size_t)B_ * NSYNC * 4);
  float* bA = (float*)alloc((size_t)B_ * NSYNC * 4);
  float* aO = (float*)alloc((size_t)B_ * NSYNC * 4);
  float* bO = (float*)alloc((size_t)B_ * NSYNC * 4);
  __hip_bfloat16* syncA = (__hip_bfloat16*)alloc((size_t)B_ * NSYNC * 2);
  __hip_bfloat16* syncO = (__hip_bfloat16*)alloc((size_t)B_ * NSYNC * 2);
  float* qhb = (float*)alloc((size_t)B_ * DIN * 4);
  __hip_bfloat16* attnv = (__hip_bfloat16*)alloc((size_t)B_ * DIN * 2);
  __hip_bfloat16* pre = (__hip_bfloat16*)alloc((size_t)B_ * (DIN + DMODEL) * 2);
  __hip_bfloat16* h1 = (__hip_bfloat16*)alloc((size_t)B_ * DMODEL * 2);
  float* nlmraw = (float*)alloc((size_t)B_ * DMODEL * 4);
  float* rAv = (float*)alloc(NSYNC * 4);
  float* rOv = (float*)alloc(NSYNC * 4);
  int* gbarrier = (int*)alloc(1024);  // 160 barrier slots (144 used)

  float* kvraw = (float*)regionA;
  __hip_bfloat16* kh = (__hip_bfloat16*)regionA;
  __hip_bfloat16* vh = (__hip_bfloat16*)(regionA + MS * DIN * 2);

  // zero barrier counters (async, captured in graph -> replays deterministically)
  hipMemsetAsync(gbarrier, 0, 1024, stream);

  dim3 t32x8(32, 8);
  // ---- weight prep ----
  transpose_bf16_kernel<<<dim3(F_ / 32, DIN / 32), t32x8, 0, stream>>>(W_kv, Wt_kv, F_, DIN, DIN);
  transpose_bf16_kernel<<<dim3(DIN / 32, DIN / 32), t32x8, 0, stream>>>(W_ak, Wt_ak, DIN, DIN, DIN);
  transpose_bf16_kernel<<<dim3(DIN / 32, DIN / 32), t32x8, 0, stream>>>(W_av, Wt_av, DIN, DIN, DIN);
  transpose_bf16_kernel<<<dim3(DIN / 32, DIN / 32), t32x8, 0, stream>>>(W_aq, Wt_aq, DIN, DIN, DIN);
  transpose_bf16_kernel<<<dim3(DIN / 32, DIN / 32), t32x8, 0, stream>>>(W_ao, Wt_ao, DIN, DIN, DIN);
  transpose_bf16_kernel<<<dim3(DMODEL / 32, (DIN + DMODEL) / 32), t32x8, 0, stream>>>(
      W_s1, Wt_s1, DIN + DMODEL, DMODEL, DMODEL);
  transpose_bf16_kernel<<<dim3(DMODEL / 32, DMODEL / 32), t32x8, 0, stream>>>(W_s2, Wt_s2, DMODEL,
                                                                              DMODEL, DMODEL);
  transpose_bf16_kernel<<<dim3((DOUT + 31) / 32, NSYNC / 32), t32x8, 0, stream>>>(
      W_out, Wt_out, NSYNC, DOUT, DOUT);
  conv_bf16_kernel<<<(NSYNC * DIN + 255) / 256, 256, 0, stream>>>(W_q, W_qb, NSYNC * DIN);
  bqaq_kernel<<<4, 256, 0, stream>>>(b_q, b_aq, Wt_aq, b_qaq);

  // ---- precompute ----
  gemm_big<0, float, float><<<dim3(DIN / 128, MS / 128), 256, 0, stream>>>(x, Wt_kv, b_kv, kvraw,
                                                                           (int)MS, DIN, F_);
  ln_kernel<__hip_bfloat16><<<(int)MS, 256, 0, stream>>>(kvraw, g_kv, be_kv, kv, DIN, DIN, 1);
  gemm_big<0, __hip_bfloat16, __hip_bfloat16><<<dim3(DIN / 128, MS / 128), 256, 0, stream>>>(
      kv, Wt_ak, b_ak, kh, (int)MS, DIN, DIN);
  gemm_big<0, __hip_bfloat16, __hip_bfloat16><<<dim3(DIN / 128, MS / 128), 256, 0, stream>>>(
      kv, Wt_av, b_av, vh, (int)MS, DIN, DIN);
  gemm_big<1, __hip_bfloat16, __hip_bfloat16><<<dim3(DIN / 128, NSYNC / 128), 256, 0, stream>>>(
      W_qb, Wt_aq, nullptr, Wt_qaq, NSYNC, DIN, DIN);

  // ---- state init ----
  init_act_kernel<<<(B_ * DMODEL + 255) / 256, 256, 0, stream>>>(init_state, act);
  init_hist_kernel<<<(B_ * DMODEL * DMEM + 255) / 256, 256, 0, stream>>>(init_hist, histf);
  init_sync_kernel<<<(B_ * NSYNC + 255) / 256, 256, 0, stream>>>(
      init_state, decay_action, decay_out, idx_la, idx_ra, idx_lo, idx_ro, aA, bA, aO, bO, syncA,
      rAv, rOv);

  // ---- persistent tick loop (regular launch; 256 blocks <= 1/CU) ----
  CArgs ca;
  ca.Wt_qaq = Wt_qaq; ca.Wt_ao = Wt_ao; ca.Wt_s1 = Wt_s1; ca.Wt_s2 = Wt_s2; ca.Wt_out = Wt_out;
  ca.kh = kh; ca.vh = vh;
  ca.b_qaq = b_qaq; ca.b_ao = b_ao; ca.b_s1 = b_s1; ca.b_s2 = b_s2; ca.b_out = b_out;
  ca.g_s = g_s; ca.be_s = be_s; ca.g_n = g_n; ca.be_n = be_n;
  ca.W_n1 = W_n1; ca.b_n1 = b_n1; ca.W_n2 = W_n2; ca.b_n2 = b_n2;
  ca.la = idx_la; ca.ra = idx_ra; ca.lo = idx_lo; ca.ro = idx_ro;
  ca.rAv = rAv; ca.rOv = rOv;
  ca.qhb = qhb; ca.part = partial; ca.histf = histf; ca.act = act;
  ca.aA = aA; ca.bA = bA; ca.aO = aO; ca.bO = bO;
  ca.nlmraw = nlmraw; ca.outp = out;
  ca.syncA = syncA; ca.syncO = syncO; ca.attnv = attnv; ca.pre = pre; ca.h1 = h1;
  ca.bar = gbarrier;

  ctm_coop<<<GPERS, 256, 0, stream>>>(ca);

  (void)in_sizes; (void)n_in; (void)out_size; (void)ws_size;
}

// Round 5
// 6311.626 us; speedup vs baseline: 1.8498x; 1.8498x over previous
//
#include <hip/hip_runtime.h>
#include <hip/hip_bf16.h>

// ---------------------------------------------------------------------------
// CTM round 4: fix software grid-barrier memory orders.
// Round-3 polled with ACQUIRE (=> buffer_inv L2 invalidate per poll per block
// => 8-XCD cache-invalidate storm, ~73us/barrier, 97% idle). Now:
//   arrive: fetch_add RELEASE (one wbl2)  |  spin: RELAXED + s_sleep
//   exit:   one ACQUIRE load (one buffer_inv)
// ---------------------------------------------------------------------------

#define B_ 64
#define S_ 512
#define F_ 1024
#define DMODEL 2048
#define DMEM 32
#define DIN 1024
#define NH 16
#define DH 64
#define DOUT 1000
#define NSYNC 512
#define TICKS 16
#define HNLM 32
#define HIST_W 48
#define GPERS 256  // persistent grid size (<= 1 block/CU -> co-resident)

typedef __attribute__((ext_vector_type(8))) short short8;
typedef __attribute__((ext_vector_type(4))) float f32x4;

__device__ inline void store_f(float* p, float v) { *p = v; }
__device__ inline void store_f(__hip_bfloat16* p, float v) { *p = __float2bfloat16(v); }

__device__ inline short f2bs(float f) {
  __hip_bfloat16 h = __float2bfloat16(f);
  return *reinterpret_cast<short*>(&h);
}

__device__ inline float gelu_f(float x) {
  float x3 = x * x * x;
  return 0.5f * x * (1.f + tanhf(0.7978845608028654f * (x + 0.044715f * x3)));
}

__device__ inline float bf_lo(unsigned v) { return __uint_as_float(v << 16); }
__device__ inline float bf_hi(unsigned v) { return __uint_as_float(v & 0xffff0000u); }

// ---------------- software grid barrier (one counter per instance) ----------
__device__ __forceinline__ void gbar(int* cnt, int idx) {
  __syncthreads();
  if (threadIdx.x == 0) {
    // RELEASE: waitcnt + wbl2, makes this block's phase writes visible device-wide
    __hip_atomic_fetch_add(&cnt[idx], 1, __ATOMIC_RELEASE, __HIP_MEMORY_SCOPE_AGENT);
    // RELAXED polling: coherent (sc1 path) but NO cache maintenance per poll
    while (__hip_atomic_load(&cnt[idx], __ATOMIC_RELAXED, __HIP_MEMORY_SCOPE_AGENT) < GPERS) {
      __builtin_amdgcn_s_sleep(16);
    }
    // single ACQUIRE: one buffer_inv so subsequent reads see other XCDs' writes
    (void)__hip_atomic_load(&cnt[idx], __ATOMIC_ACQUIRE, __HIP_MEMORY_SCOPE_AGENT);
  }
  __syncthreads();
}

// ---------------- weight prep ----------------
__global__ __launch_bounds__(256) void transpose_bf16_kernel(const float* __restrict__ W,
                                                             __hip_bfloat16* __restrict__ Wt,
                                                             int K, int N, int Npad) {
  __shared__ float t[32][33];
  const int tx = threadIdx.x, ty = threadIdx.y;  // 32 x 8
  const int n0 = blockIdx.x * 32, k0 = blockIdx.y * 32;
#pragma unroll
  for (int i = 0; i < 4; i++) {
    int k = k0 + ty + i * 8;
    t[ty + i * 8][tx] = (k < K && n0 + tx < N) ? W[(size_t)k * N + n0 + tx] : 0.f;
  }
  __syncthreads();
#pragma unroll
  for (int i = 0; i < 4; i++) {
    int n = n0 + ty + i * 8;
    if (n < Npad && k0 + tx < K)
      Wt[(size_t)n * K + k0 + tx] = __float2bfloat16(t[tx][ty + i * 8]);
  }
}

__global__ void conv_bf16_kernel(const float* __restrict__ src, __hip_bfloat16* __restrict__ dst,
                                 int n) {
  int i = blockIdx.x * 256 + threadIdx.x;
  if (i < n) dst[i] = __float2bfloat16(src[i]);
}

__global__ void bqaq_kernel(const float* __restrict__ b_q, const float* __restrict__ b_aq,
                            const __hip_bfloat16* __restrict__ Wt_aq, float* __restrict__ b_qaq) {
  int n = blockIdx.x * 256 + threadIdx.x;
  if (n >= DIN) return;
  const __hip_bfloat16* wr = Wt_aq + (size_t)n * DIN;
  float s = b_aq[n];
  for (int k = 0; k < DIN; k++) s += b_q[k] * __bfloat162float(wr[k]);
  b_qaq[n] = s;
}

// ---------------- big MFMA GEMM (precompute) ----------------
__device__ inline short8 load_chunk(const __hip_bfloat16* p) {
  return *reinterpret_cast<const short8*>(p);
}
__device__ inline short8 load_chunk(const float* p) {
  short8 r;
#pragma unroll
  for (int j = 0; j < 8; j++) r[j] = f2bs(p[j]);
  return r;
}

template <int TRANSC, typename TA, typename TC>
__global__ __launch_bounds__(256) void gemm_big(const TA* __restrict__ A,
                                                const __hip_bfloat16* __restrict__ Bt,
                                                const float* __restrict__ bias,
                                                TC* __restrict__ C, int M, int N, int K) {
  __shared__ short lsA[128 * 64];
  __shared__ short lsB[128 * 64];
  const int tid = threadIdx.x;
  const int l = tid & 63, w = tid >> 6;
  const int wr = (w >> 1) * 64, wc = (w & 1) * 64;
  const int brow = blockIdx.y * 128, bcol = blockIdx.x * 128;
  f32x4 acc[4][4];
#pragma unroll
  for (int i = 0; i < 4; i++)
#pragma unroll
    for (int j = 0; j < 4; j++)
#pragma unroll
      for (int r = 0; r < 4; r++) acc[i][j][r] = 0.f;

  short8 ra[4], rb[4];
  auto gload = [&](int k0) {
#pragma unroll
    for (int q = 0; q < 4; q++) {
      int i = tid + q * 256;
      int row = i >> 3, c = i & 7;
      ra[q] = load_chunk(A + (size_t)(brow + row) * K + k0 + c * 8);
      rb[q] = load_chunk(Bt + (size_t)(bcol + row) * K + k0 + c * 8);
    }
  };
  auto lwrite = [&]() {
#pragma unroll
    for (int q = 0; q < 4; q++) {
      int i = tid + q * 256;
      int row = i >> 3, c = i & 7;
      int sw = c ^ (row & 7);
      *reinterpret_cast<short8*>(&lsA[row * 64 + sw * 8]) = ra[q];
      *reinterpret_cast<short8*>(&lsB[row * 64 + sw * 8]) = rb[q];
    }
  };
  gload(0);
  for (int k0 = 0; k0 < K; k0 += 64) {
    __syncthreads();
    lwrite();
    if (k0 + 64 < K) gload(k0 + 64);
    __syncthreads();
#pragma unroll
    for (int ks = 0; ks < 2; ks++) {
      short8 af[4], bfv[4];
#pragma unroll
      for (int mi = 0; mi < 4; mi++) {
        int row = wr + mi * 16 + (l & 15);
        int c = ks * 4 + (l >> 4);
        af[mi] = *reinterpret_cast<const short8*>(&lsA[row * 64 + (c ^ (row & 7)) * 8]);
      }
#pragma unroll
      for (int ni = 0; ni < 4; ni++) {
        int row = wc + ni * 16 + (l & 15);
        int c = ks * 4 + (l >> 4);
        bfv[ni] = *reinterpret_cast<const short8*>(&lsB[row * 64 + (c ^ (row & 7)) * 8]);
      }
#pragma unroll
      for (int mi = 0; mi < 4; mi++)
#pragma unroll
        for (int ni = 0; ni < 4; ni++)
          acc[mi][ni] =
              __builtin_amdgcn_mfma_f32_16x16x32_bf16(af[mi], bfv[ni], acc[mi][ni], 0, 0, 0);
    }
  }
#pragma unroll
  for (int mi = 0; mi < 4; mi++)
#pragma unroll
    for (int ni = 0; ni < 4; ni++)
#pragma unroll
      for (int r = 0; r < 4; r++) {
        int row = brow + wr + mi * 16 + (l >> 4) * 4 + r;
        int col = bcol + wc + ni * 16 + (l & 15);
        float v = acc[mi][ni][r];
        if (bias) v += bias[col];
        if (TRANSC)
          store_f(&C[(size_t)col * M + row], v);
        else
          store_f(&C[(size_t)row * N + col], v);
      }
}

// ---------------- LayerNorm (precompute: kv) ----------------
template <typename TOUT>
__global__ __launch_bounds__(256) void ln_kernel(const float* __restrict__ x,
                                                 const float* __restrict__ g,
                                                 const float* __restrict__ be,
                                                 TOUT* __restrict__ out, int C,
                                                 size_t row_stride, int col_stride) {
  const int row = blockIdx.x;
  const int tid = threadIdx.x;
  const float* xr = x + (size_t)row * C;
  float s = 0.f, s2 = 0.f;
  for (int c = tid; c < C; c += 256) {
    float v = xr[c];
    s += v;
    s2 += v * v;
  }
  __shared__ float r1[256], r2[256];
  r1[tid] = s;
  r2[tid] = s2;
  __syncthreads();
  for (int st = 128; st > 0; st >>= 1) {
    if (tid < st) {
      r1[tid] += r1[tid + st];
      r2[tid] += r2[tid + st];
    }
    __syncthreads();
  }
  float mean = r1[0] / C;
  float var = r2[0] / C - mean * mean;
  float inv = 1.0f / sqrtf(var + 1e-5f);
  for (int c = tid; c < C; c += 256) {
    float v = (xr[c] - mean) * inv * g[c] + be[c];
    store_f(&out[(size_t)row * row_stride + (size_t)c * col_stride], v);
  }
}

// ---------------- init kernels ----------------
__global__ void init_act_kernel(const float* __restrict__ init_state, float* __restrict__ act) {
  int i = blockIdx.x * 256 + threadIdx.x;
  if (i < B_ * DMODEL) act[i] = init_state[i & (DMODEL - 1)];
}

__global__ void init_hist_kernel(const float* __restrict__ init_hist, float* __restrict__ hist) {
  int i = blockIdx.x * 256 + threadIdx.x;
  if (i >= B_ * DMODEL * DMEM) return;
  int m = i & (DMEM - 1);
  int bd = i >> 5;
  int d = bd & (DMODEL - 1);
  hist[(size_t)bd * HIST_W + m] = init_hist[d * DMEM + m];
}

// also precomputes rA/rO and tick-0 action-sync state
__global__ void init_sync_kernel(const float* __restrict__ init_state,
                                 const float* __restrict__ decay_action,
                                 const float* __restrict__ decay_out,
                                 const int* __restrict__ la, const int* __restrict__ ra,
                                 const int* __restrict__ lo, const int* __restrict__ ro,
                                 float* __restrict__ aA, float* __restrict__ bA,
                                 float* __restrict__ aO, float* __restrict__ bO,
                                 __hip_bfloat16* __restrict__ syncA, float* __restrict__ rAv,
                                 float* __restrict__ rOv) {
  int i = blockIdx.x * 256 + threadIdx.x;
  if (i >= B_ * NSYNC) return;
  int j = i & (NSYNC - 1);
  if (i < NSYNC) {
    rAv[i] = expf(-fminf(fmaxf(decay_action[i], 0.f), 15.f));
    rOv[i] = expf(-fminf(fmaxf(decay_out[i], 0.f), 15.f));
  }
  float pA = init_state[la[j]] * init_state[ra[j]];
  aA[i] = pA;
  bA[i] = 1.f;
  syncA[i] = __float2bfloat16(pA);  // pA / sqrt(1)
  aO[i] = init_state[lo[j]] * init_state[ro[j]];
  bO[i] = 1.f;
}

// ---------------- persistent tick kernel ----------------
struct CArgs {
  const __hip_bfloat16 *Wt_qaq, *Wt_ao, *Wt_s1, *Wt_s2, *Wt_out;
  const __hip_bfloat16 *kh, *vh;
  const float *b_qaq, *b_ao, *b_s1, *b_s2, *b_out;
  const float *g_s, *be_s, *g_n, *be_n;
  const float *W_n1, *b_n1, *W_n2, *b_n2;
  const int *la, *ra, *lo, *ro;
  const float *rAv, *rOv;
  float *qhb, *part, *histf, *act, *aA, *bA, *aO, *bO, *nlmraw, *outp;
  __hip_bfloat16 *syncA, *syncO, *attnv, *pre, *h1;
  int* bar;
};

// one 64xN-tile MFMA matmul step: C-tile rows 0..63, cols [bcol,bcol+64), K in [kb,kb+kchunk)
template <typename EPI>
__device__ __forceinline__ void mm_tile64(const __hip_bfloat16* __restrict__ A, int lda,
                                          const __hip_bfloat16* __restrict__ Bt, int ldb,
                                          int bcol, int kb, int kchunk, short* lsA, short* lsB,
                                          EPI epi) {
  const int tid = threadIdx.x;
  const int l = tid & 63, w = tid >> 6;
  f32x4 acc[4];
#pragma unroll
  for (int i = 0; i < 4; i++)
#pragma unroll
    for (int r = 0; r < 4; r++) acc[i][r] = 0.f;
  short8 ra[2], rb[2];
  auto gload = [&](int k0) {
#pragma unroll
    for (int q = 0; q < 2; q++) {
      int i = tid + q * 256;
      int row = i >> 3, c = i & 7;
      ra[q] = *reinterpret_cast<const short8*>(A + (size_t)row * lda + k0 + c * 8);
      rb[q] = *reinterpret_cast<const short8*>(Bt + (size_t)(bcol + row) * ldb + k0 + c * 8);
    }
  };
  auto lwrite = [&]() {
#pragma unroll
    for (int q = 0; q < 2; q++) {
      int i = tid + q * 256;
      int row = i >> 3, c = i & 7;
      int sw = c ^ (row & 7);
      *reinterpret_cast<short8*>(&lsA[row * 64 + sw * 8]) = ra[q];
      *reinterpret_cast<short8*>(&lsB[row * 64 + sw * 8]) = rb[q];
    }
  };
  gload(kb);
  for (int k0 = kb; k0 < kb + kchunk; k0 += 64) {
    __syncthreads();
    lwrite();
    if (k0 + 64 < kb + kchunk) gload(k0 + 64);
    __syncthreads();
#pragma unroll
    for (int ks = 0; ks < 2; ks++) {
      int rowa = w * 16 + (l & 15);
      int c = ks * 4 + (l >> 4);
      short8 af = *reinterpret_cast<const short8*>(&lsA[rowa * 64 + (c ^ (rowa & 7)) * 8]);
#pragma unroll
      for (int ni = 0; ni < 4; ni++) {
        int rowb = ni * 16 + (l & 15);
        short8 bfv = *reinterpret_cast<const short8*>(&lsB[rowb * 64 + (c ^ (rowb & 7)) * 8]);
        acc[ni] = __builtin_amdgcn_mfma_f32_16x16x32_bf16(af, bfv, acc[ni], 0, 0, 0);
      }
    }
  }
#pragma unroll
  for (int ni = 0; ni < 4; ni++)
#pragma unroll
    for (int r = 0; r < 4; r++) {
      int m = w * 16 + (l >> 4) * 4 + r;
      int n = bcol + ni * 16 + (l & 15);
      epi(m, n, acc[ni][r]);
    }
}

__global__ __launch_bounds__(256) void ctm_coop(CArgs a) {
  __shared__ __align__(16) char smem[17408];
  short* lsA = (short*)smem;
  short* lsB = (short*)(smem + 8192);
  float* sf = (float*)smem;
  const int tid = threadIdx.x;
  const int gbx = blockIdx.x;
  const int G = GPERS;
  int bi = 0;  // barrier instance index (same sequence on all blocks)

  for (int t = 0; t < TICKS; ++t) {
    // ---- P1: qh = syncA @ (W_q W_aq) + b_qaq ; pack act -> pre[:,1024:] ----
    for (int u = gbx; u < 16; u += G)
      mm_tile64(a.syncA, NSYNC, a.Wt_qaq, NSYNC, u * 64, 0, NSYNC, lsA, lsB,
                [&](int m, int n, float v) { a.qhb[m * DIN + n] = v + a.b_qaq[n]; });
    if (gbx >= 16) {
      int stride = (G - 16) * 256;
      for (int i = (gbx - 16) * 256 + tid; i < B_ * DMODEL; i += stride) {
        int b = i >> 11, j = i & (DMODEL - 1);
        a.pre[(size_t)b * 3072 + DIN + j] = __float2bfloat16(a.act[i]);
      }
    }
    gbar(a.bar, bi++);
    // ---- P2: attention ----
    for (int u = gbx; u < B_ * NH; u += G) {
      const int b = u >> 4, h = u & (NH - 1);
      float* qs = sf;
      float* wv = sf + 64;
      float* red = sf + 576;
      if (tid < DH) qs[tid] = a.qhb[b * DIN + h * DH + tid];
      __syncthreads();
      float sc[2];
#pragma unroll
      for (int r = 0; r < 2; ++r) {
        int s = tid + r * 256;
        const unsigned* kp =
            reinterpret_cast<const unsigned*>(a.kh + ((size_t)(b * S_ + s) * DIN + h * DH));
        float accv = 0.f;
#pragma unroll
        for (int q = 0; q < DH / 2; ++q) {
          unsigned uu = kp[q];
          accv += qs[q * 2 + 0] * bf_lo(uu) + qs[q * 2 + 1] * bf_hi(uu);
        }
        sc[r] = accv * 0.125f;
      }
      red[tid] = fmaxf(sc[0], sc[1]);
      __syncthreads();
      for (int st = 128; st > 0; st >>= 1) {
        if (tid < st) red[tid] = fmaxf(red[tid], red[tid + st]);
        __syncthreads();
      }
      const float mx = red[0];
      __syncthreads();
      float e0 = expf(sc[0] - mx), e1 = expf(sc[1] - mx);
      wv[tid] = e0;
      wv[tid + 256] = e1;
      red[tid] = e0 + e1;
      __syncthreads();
      for (int st = 128; st > 0; st >>= 1) {
        if (tid < st) red[tid] += red[tid + st];
        __syncthreads();
      }
      const float invZ = 1.f / red[0];
      __syncthreads();
      const int d = tid & 63, g2 = tid >> 6;
      const __hip_bfloat16* vp = a.vh + ((size_t)b * S_ * DIN + (size_t)h * DH + d);
      float accv = 0.f;
      for (int s = g2; s < S_; s += 4) accv += wv[s] * __bfloat162float(vp[(size_t)s * DIN]);
      red[tid] = accv;
      __syncthreads();
      if (tid < 64) {
        float r = red[tid] + red[64 + tid] + red[128 + tid] + red[192 + tid];
        a.attnv[b * DIN + h * DH + tid] = __float2bfloat16(r * invZ);
      }
      __syncthreads();
    }
    gbar(a.bar, bi++);
    // ---- P3: ao GEMM -> pre[:, :1024] ----
    for (int u = gbx; u < 16; u += G)
      mm_tile64(a.attnv, DIN, a.Wt_ao, DIN, u * 64, 0, DIN, lsA, lsB, [&](int m, int n, float v) {
        a.pre[(size_t)m * 3072 + n] = __float2bfloat16(v + a.b_ao[n]);
      });
    gbar(a.bar, bi++);
    // ---- P4: s1 GEMM split-K8 ----
    for (int u = gbx; u < 256; u += G) {
      int nt = u & 31, ks = u >> 5;
      mm_tile64(a.pre, 3072, a.Wt_s1, 3072, nt * 64, ks * 384, 384, lsA, lsB,
                [&](int m, int n, float v) { a.part[((size_t)ks * 64 + m) * DMODEL + n] = v; });
    }
    gbar(a.bar, bi++);
    // ---- P5: s1 reduce + gelu -> h1 ----
    for (int u = gbx; u < 64; u += G) {
      for (int i = 0; i < 8; i++) {
        int n = tid + i * 256;
        float s = a.b_s1[n];
        for (int ks = 0; ks < 8; ks++) s += a.part[((size_t)ks * 64 + u) * DMODEL + n];
        a.h1[(size_t)u * DMODEL + n] = __float2bfloat16(gelu_f(s));
      }
    }
    gbar(a.bar, bi++);
    // ---- P6: s2 GEMM split-K8 ----
    for (int u = gbx; u < 256; u += G) {
      int nt = u & 31, ks = u >> 5;
      mm_tile64(a.h1, DMODEL, a.Wt_s2, DMODEL, nt * 64, ks * 256, 256, lsA, lsB,
                [&](int m, int n, float v) { a.part[((size_t)ks * 64 + m) * DMODEL + n] = v; });
    }
    gbar(a.bar, bi++);
    // ---- P7: s2 reduce + LN -> hist slot 32+t ----
    for (int u = gbx; u < 64; u += G) {
      float v[8];
      float s = 0.f, s2 = 0.f;
      for (int i = 0; i < 8; i++) {
        int n = tid + i * 256;
        float x = a.b_s2[n];
        for (int ks = 0; ks < 8; ks++) x += a.part[((size_t)ks * 64 + u) * DMODEL + n];
        v[i] = x;
        s += x;
        s2 += x * x;
      }
      float* r1 = sf;
      float* r2 = sf + 256;
      r1[tid] = s;
      r2[tid] = s2;
      __syncthreads();
      for (int st = 128; st > 0; st >>= 1) {
        if (tid < st) {
          r1[tid] += r1[tid + st];
          r2[tid] += r2[tid + st];
        }
        __syncthreads();
      }
      float mean = r1[0] / DMODEL;
      float var = r2[0] / DMODEL - mean * mean;
      float inv = 1.f / sqrtf(var + 1e-5f);
      __syncthreads();
      for (int i = 0; i < 8; i++) {
        int n = tid + i * 256;
        float pa = (v[i] - mean) * inv * a.g_s[n] + a.be_s[n];
        a.histf[((size_t)u * DMODEL + n) * HIST_W + 32 + t] = pa;
      }
      __syncthreads();
    }
    gbar(a.bar, bi++);
    // ---- P8: NLM ----
    for (int u = gbx; u < 512; u += G) {
      float* w1s = sf;         // 4096 f
      float* b1s = sf + 4096;  // 128 f
      int d0 = u * 4;
      for (int i = tid; i < 4096; i += 256) w1s[i] = a.W_n1[(size_t)d0 * 1024 + i];
      if (tid < 128) b1s[tid] = a.b_n1[d0 * 32 + tid];
      __syncthreads();
      int b = tid & 63, dsub = tid >> 6;
      int d = d0 + dsub;
      const float* hw = a.histf + ((size_t)(b * DMODEL + d)) * HIST_W + t + 1;
      float win[DMEM];
#pragma unroll
      for (int m = 0; m < DMEM; ++m) win[m] = hw[m];
      const float* w1 = w1s + dsub * 1024;
      const float* bb = b1s + dsub * 32;
      const float* w2 = a.W_n2 + d * HNLM;
      float acc = 0.f;
      for (int h = 0; h < HNLM; ++h) {
        float s = bb[h];
#pragma unroll
        for (int m = 0; m < DMEM; ++m) s += win[m] * w1[m * HNLM + h];
        acc += fmaxf(s, 0.f) * w2[h];
      }
      a.nlmraw[(size_t)b * DMODEL + d] = acc + a.b_n2[d];
      __syncthreads();
    }
    gbar(a.bar, bi++);
    // ---- P9: LN(nlmraw) -> act ; syncA(t+1), syncO(t) ----
    for (int u = gbx; u < 64; u += G) {
      const float* xr = a.nlmraw + (size_t)u * DMODEL;
      float* arow = sf;         // 2048 f
      float* r1 = sf + 2048;    // 256 f
      float* r2 = sf + 2304;    // 256 f
      float xv[8];
      float s = 0.f, s2 = 0.f;
      for (int i = 0; i < 8; i++) {
        float x = xr[tid + i * 256];
        xv[i] = x;
        s += x;
        s2 += x * x;
      }
      r1[tid] = s;
      r2[tid] = s2;
      __syncthreads();
      for (int st = 128; st > 0; st >>= 1) {
        if (tid < st) {
          r1[tid] += r1[tid + st];
          r2[tid] += r2[tid + st];
        }
        __syncthreads();
      }
      float mean = r1[0] / DMODEL;
      float var = r2[0] / DMODEL - mean * mean;
      float inv = 1.f / sqrtf(var + 1e-5f);
      __syncthreads();
      for (int i = 0; i < 8; i++) {
        int n = tid + i * 256;
        float av = (xv[i] - mean) * inv * a.g_n[n] + a.be_n[n];
        a.act[(size_t)u * DMODEL + n] = av;
        arow[n] = av;
      }
      __syncthreads();
      for (int j = tid; j < NSYNC; j += 256) {
        size_t idx = (size_t)u * NSYNC + j;
        float pA = arow[a.la[j]] * arow[a.ra[j]];
        float r = a.rAv[j];
        float av2 = r * a.aA[idx] + pA, bv2 = r * a.bA[idx] + 1.f;
        a.aA[idx] = av2;
        a.bA[idx] = bv2;
        a.syncA[idx] = __float2bfloat16(av2 / sqrtf(bv2));
        float pO = arow[a.lo[j]] * arow[a.ro[j]];
        float ro = a.rOv[j];
        av2 = ro * a.aO[idx] + pO;
        bv2 = ro * a.bO[idx] + 1.f;
        a.aO[idx] = av2;
        a.bO[idx] = bv2;
        a.syncO[idx] = __float2bfloat16(av2 / sqrtf(bv2));
      }
      __syncthreads();
    }
    gbar(a.bar, bi++);
    // ---- P10: output head (GEMV + entropy); no trailing barrier needed ----
    for (int u = gbx; u < 64; u += G) {
      float* so = sf;          // 512 f
      float* pv = sf + 512;    // 1024 f
      float* red = sf + 1536;  // 256 f
      so[tid] = __bfloat162float(a.syncO[(size_t)u * NSYNC + tid]);
      so[tid + 256] = __bfloat162float(a.syncO[(size_t)u * NSYNC + 256 + tid]);
      __syncthreads();
      float pr[4];
#pragma unroll
      for (int i = 0; i < 4; i++) {
        int n = tid + i * 256;
        pr[i] = 0.f;
        if (n < DOUT) {
          const unsigned* wr = reinterpret_cast<const unsigned*>(a.Wt_out + (size_t)n * NSYNC);
          float sacc = a.b_out[n];
          for (int c = 0; c < 256; c++) {
            unsigned uu = wr[c];
            sacc += so[2 * c] * bf_lo(uu) + so[2 * c + 1] * bf_hi(uu);
          }
          pr[i] = sacc;
          pv[n] = sacc;
        }
      }
      __syncthreads();
      float m = -1e30f;
      for (int o = tid; o < DOUT; o += 256) m = fmaxf(m, pv[o]);
      red[tid] = m;
      __syncthreads();
      for (int st = 128; st > 0; st >>= 1) {
        if (tid < st) red[tid] = fmaxf(red[tid], red[tid + st]);
        __syncthreads();
      }
      m = red[0];
      __syncthreads();
      float z = 0.f, s1 = 0.f;
      for (int o = tid; o < DOUT; o += 256) {
        float wv2 = pv[o] - m;
        float e = expf(wv2);
        z += e;
        s1 += e * wv2;
      }
      red[tid] = z;
      __syncthreads();
      for (int st = 128; st > 0; st >>= 1) {
        if (tid < st) red[tid] += red[tid + st];
        __syncthreads();
      }
      const float Z = red[0];
      __syncthreads();
      red[tid] = s1;
      __syncthreads();
      for (int st = 128; st > 0; st >>= 1) {
        if (tid < st) red[tid] += red[tid + st];
        __syncthreads();
      }
      const float S1 = red[0];
      const float ne = -(S1 / Z - logf(Z)) / 6.907755278982137f;
#pragma unroll
      for (int i = 0; i < 4; i++) {
        int n = tid + i * 256;
        if (n < DOUT) a.outp[((size_t)u * DOUT + n) * TICKS + t] = pr[i];
      }
      if (tid == 0) {
        float* c = a.outp + (size_t)B_ * DOUT * TICKS;
        c[u * 2 * TICKS + t] = ne;
        c[u * 2 * TICKS + TICKS + t] = 1.f - ne;
      }
      __syncthreads();
    }
  }
}

// ---------------------------------------------------------------------------
extern "C" void kernel_launch(void* const* d_in, const int* in_sizes, int n_in,
                              void* d_out, int out_size, void* d_ws, size_t ws_size,
                              hipStream_t stream) {
  const float* x = (const float*)d_in[0];
  const float* W_kv = (const float*)d_in[1];
  const float* b_kv = (const float*)d_in[2];
  const float* g_kv = (const float*)d_in[3];
  const float* be_kv = (const float*)d_in[4];
  const float* W_q = (const float*)d_in[5];
  const float* b_q = (const float*)d_in[6];
  const float* W_aq = (const float*)d_in[7];
  const float* b_aq = (const float*)d_in[8];
  const float* W_ak = (const float*)d_in[9];
  const float* b_ak = (const float*)d_in[10];
  const float* W_av = (const float*)d_in[11];
  const float* b_av = (const float*)d_in[12];
  const float* W_ao = (const float*)d_in[13];
  const float* b_ao = (const float*)d_in[14];
  const float* W_s1 = (const float*)d_in[15];
  const float* b_s1 = (const float*)d_in[16];
  const float* W_s2 = (const float*)d_in[17];
  const float* b_s2 = (const float*)d_in[18];
  const float* g_s = (const float*)d_in[19];
  const float* be_s = (const float*)d_in[20];
  const float* W_n1 = (const float*)d_in[21];
  const float* b_n1 = (const float*)d_in[22];
  const float* W_n2 = (const float*)d_in[23];
  const float* b_n2 = (const float*)d_in[24];
  const float* g_n = (const float*)d_in[25];
  const float* be_n = (const float*)d_in[26];
  const float* init_state = (const float*)d_in[27];
  const float* init_hist = (const float*)d_in[28];
  const float* decay_action = (const float*)d_in[29];
  const float* decay_out = (const float*)d_in[30];
  const float* W_out = (const float*)d_in[31];
  const float* b_out = (const float*)d_in[32];
  const int* idx_la = (const int*)d_in[33];
  const int* idx_ra = (const int*)d_in[34];
  const int* idx_lo = (const int*)d_in[35];
  const int* idx_ro = (const int*)d_in[36];
  float* out = (float*)d_out;

  // ---- workspace carve ----
  char* wsb = (char*)d_ws;
  size_t off = 0;
  auto alloc = [&](size_t bytes) -> char* {
    char* p = wsb + off;
    off += (bytes + 255) & ~(size_t)255;
    return p;
  };
  const size_t MS = (size_t)B_ * S_;  // 32768
  char* regionA = alloc(MS * DIN * 4);  // kvraw fp32; later kh+vh bf16
  __hip_bfloat16* kv = (__hip_bfloat16*)alloc(MS * DIN * 2);
  float* histf = (float*)alloc((size_t)B_ * DMODEL * HIST_W * 4);
  __hip_bfloat16* Wt_kv = (__hip_bfloat16*)alloc((size_t)DIN * F_ * 2);
  __hip_bfloat16* Wt_ak = (__hip_bfloat16*)alloc((size_t)DIN * DIN * 2);
  __hip_bfloat16* Wt_av = (__hip_bfloat16*)alloc((size_t)DIN * DIN * 2);
  __hip_bfloat16* Wt_aq = (__hip_bfloat16*)alloc((size_t)DIN * DIN * 2);
  __hip_bfloat16* Wt_ao = (__hip_bfloat16*)alloc((size_t)DIN * DIN * 2);
  __hip_bfloat16* W_qb = (__hip_bfloat16*)alloc((size_t)NSYNC * DIN * 2);
  __hip_bfloat16* Wt_qaq = (__hip_bfloat16*)alloc((size_t)DIN * NSYNC * 2);
  __hip_bfloat16* Wt_s1 = (__hip_bfloat16*)alloc((size_t)DMODEL * (DIN + DMODEL) * 2);
  __hip_bfloat16* Wt_s2 = (__hip_bfloat16*)alloc((size_t)DMODEL * DMODEL * 2);
  __hip_bfloat16* Wt_out = (__hip_bfloat16*)alloc((size_t)DOUT * NSYNC * 2);
  float* b_qaq = (float*)alloc(DIN * 4);
  float* partial = (float*)alloc((size_t)8 * 64 * DMODEL * 4);
  float* act = (float*)alloc((size_t)B_ * DMODEL * 4);
  float* aA = (float*)alloc((size_t)B_ * NSYNC * 4);
  float* bA = (float*)alloc((size_t)B_ * NSYNC * 4);
  float* aO = (float*)alloc((size_t)B_ * NSYNC * 4);
  float* bO = (float*)alloc((size_t)B_ * NSYNC * 4);
  __hip_bfloat16* syncA = (__hip_bfloat16*)alloc((size_t)B_ * NSYNC * 2);
  __hip_bfloat16* syncO = (__hip_bfloat16*)alloc((size_t)B_ * NSYNC * 2);
  float* qhb = (float*)alloc((size_t)B_ * DIN * 4);
  __hip_bfloat16* attnv = (__hip_bfloat16*)alloc((size_t)B_ * DIN * 2);
  __hip_bfloat16* pre = (__hip_bfloat16*)alloc((size_t)B_ * (DIN + DMODEL) * 2);
  __hip_bfloat16* h1 = (__hip_bfloat16*)alloc((size_t)B_ * DMODEL * 2);
  float* nlmraw = (float*)alloc((size_t)B_ * DMODEL * 4);
  float* rAv = (float*)alloc(NSYNC * 4);
  float* rOv = (float*)alloc(NSYNC * 4);
  int* gbarrier = (int*)alloc(1024);  // 160 barrier slots (144 used)

  float* kvraw = (float*)regionA;
  __hip_bfloat16* kh = (__hip_bfloat16*)regionA;
  __hip_bfloat16* vh = (__hip_bfloat16*)(regionA + MS * DIN * 2);

  // zero barrier counters (async, captured in graph -> replays deterministically)
  hipMemsetAsync(gbarrier, 0, 1024, stream);

  dim3 t32x8(32, 8);
  // ---- weight prep ----
  transpose_bf16_kernel<<<dim3(F_ / 32, DIN / 32), t32x8, 0, stream>>>(W_kv, Wt_kv, F_, DIN, DIN);
  transpose_bf16_kernel<<<dim3(DIN / 32, DIN / 32), t32x8, 0, stream>>>(W_ak, Wt_ak, DIN, DIN, DIN);
  transpose_bf16_kernel<<<dim3(DIN / 32, DIN / 32), t32x8, 0, stream>>>(W_av, Wt_av, DIN, DIN, DIN);
  transpose_bf16_kernel<<<dim3(DIN / 32, DIN / 32), t32x8, 0, stream>>>(W_aq, Wt_aq, DIN, DIN, DIN);
  transpose_bf16_kernel<<<dim3(DIN / 32, DIN / 32), t32x8, 0, stream>>>(W_ao, Wt_ao, DIN, DIN, DIN);
  transpose_bf16_kernel<<<dim3(DMODEL / 32, (DIN + DMODEL) / 32), t32x8, 0, stream>>>(
      W_s1, Wt_s1, DIN + DMODEL, DMODEL, DMODEL);
  transpose_bf16_kernel<<<dim3(DMODEL / 32, DMODEL / 32), t32x8, 0, stream>>>(W_s2, Wt_s2, DMODEL,
                                                                              DMODEL, DMODEL);
  transpose_bf16_kernel<<<dim3((DOUT + 31) / 32, NSYNC / 32), t32x8, 0, stream>>>(
      W_out, Wt_out, NSYNC, DOUT, DOUT);
  conv_bf16_kernel<<<(NSYNC * DIN + 255) / 256, 256, 0, stream>>>(W_q, W_qb, NSYNC * DIN);
  bqaq_kernel<<<4, 256, 0, stream>>>(b_q, b_aq, Wt_aq, b_qaq);

  // ---- precompute ----
  gemm_big<0, float, float><<<dim3(DIN / 128, MS / 128), 256, 0, stream>>>(x, Wt_kv, b_kv, kvraw,
                                                                           (int)MS, DIN, F_);
  ln_kernel<__hip_bfloat16><<<(int)MS, 256, 0, stream>>>(kvraw, g_kv, be_kv, kv, DIN, DIN, 1);
  gemm_big<0, __hip_bfloat16, __hip_bfloat16><<<dim3(DIN / 128, MS / 128), 256, 0, stream>>>(
      kv, Wt_ak, b_ak, kh, (int)MS, DIN, DIN);
  gemm_big<0, __hip_bfloat16, __hip_bfloat16><<<dim3(DIN / 128, MS / 128), 256, 0, stream>>>(
      kv, Wt_av, b_av, vh, (int)MS, DIN, DIN);
  gemm_big<1, __hip_bfloat16, __hip_bfloat16><<<dim3(DIN / 128, NSYNC / 128), 256, 0, stream>>>(
      W_qb, Wt_aq, nullptr, Wt_qaq, NSYNC, DIN, DIN);

  // ---- state init ----
  init_act_kernel<<<(B_ * DMODEL + 255) / 256, 256, 0, stream>>>(init_state, act);
  init_hist_kernel<<<(B_ * DMODEL * DMEM + 255) / 256, 256, 0, stream>>>(init_hist, histf);
  init_sync_kernel<<<(B_ * NSYNC + 255) / 256, 256, 0, stream>>>(
      init_state, decay_action, decay_out, idx_la, idx_ra, idx_lo, idx_ro, aA, bA, aO, bO, syncA,
      rAv, rOv);

  // ---- persistent tick loop (regular launch; 256 blocks <= 1/CU) ----
  CArgs ca;
  ca.Wt_qaq = Wt_qaq; ca.Wt_ao = Wt_ao; ca.Wt_s1 = Wt_s1; ca.Wt_s2 = Wt_s2; ca.Wt_out = Wt_out;
  ca.kh = kh; ca.vh = vh;
  ca.b_qaq = b_qaq; ca.b_ao = b_ao; ca.b_s1 = b_s1; ca.b_s2 = b_s2; ca.b_out = b_out;
  ca.g_s = g_s; ca.be_s = be_s; ca.g_n = g_n; ca.be_n = be_n;
  ca.W_n1 = W_n1; ca.b_n1 = b_n1; ca.W_n2 = W_n2; ca.b_n2 = b_n2;
  ca.la = idx_la; ca.ra = idx_ra; ca.lo = idx_lo; ca.ro = idx_ro;
  ca.rAv = rAv; ca.rOv = rOv;
  ca.qhb = qhb; ca.part = partial; ca.histf = histf; ca.act = act;
  ca.aA = aA; ca.bA = bA; ca.aO = aO; ca.bO = bO;
  ca.nlmraw = nlmraw; ca.outp = out;
  ca.syncA = syncA; ca.syncO = syncO; ca.attnv = attnv; ca.pre = pre; ca.h1 = h1;
  ca.bar = gbarrier;

  ctm_coop<<<GPERS, 256, 0, stream>>>(ca);

  (void)in_sizes; (void)n_in; (void)out_size; (void)ws_size;
}

// Round 6
// 4791.962 us; speedup vs baseline: 2.4365x; 1.3171x over previous
//
#include <hip/hip_runtime.h>
#include <hip/hip_bf16.h>

// ---------------------------------------------------------------------------
// CTM round 5: attention made streaming-friendly.
//  - kh/vh stored head-major [b][h][s][d] via GEMM epilogue (TRANSC=2)
//  - QK/PV fully coalesced (short8 per lane), PV via 32-group LDS reduce
//  - removed P9->P10 barrier (same-block producer/consumer)
// Persistent-kernel structure and software grid barrier unchanged (round 4).
// ---------------------------------------------------------------------------

#define B_ 64
#define S_ 512
#define F_ 1024
#define DMODEL 2048
#define DMEM 32
#define DIN 1024
#define NH 16
#define DH 64
#define DOUT 1000
#define NSYNC 512
#define TICKS 16
#define HNLM 32
#define HIST_W 48
#define GPERS 256  // persistent grid size (<= 1 block/CU -> co-resident)

typedef __attribute__((ext_vector_type(8))) short short8;
typedef __attribute__((ext_vector_type(4))) float f32x4;

__device__ inline void store_f(float* p, float v) { *p = v; }
__device__ inline void store_f(__hip_bfloat16* p, float v) { *p = __float2bfloat16(v); }

__device__ inline short f2bs(float f) {
  __hip_bfloat16 h = __float2bfloat16(f);
  return *reinterpret_cast<short*>(&h);
}

__device__ inline float bfs(short x) {
  return __uint_as_float(((unsigned)(unsigned short)x) << 16);
}

__device__ inline float gelu_f(float x) {
  float x3 = x * x * x;
  return 0.5f * x * (1.f + tanhf(0.7978845608028654f * (x + 0.044715f * x3)));
}

__device__ inline float bf_lo(unsigned v) { return __uint_as_float(v << 16); }
__device__ inline float bf_hi(unsigned v) { return __uint_as_float(v & 0xffff0000u); }

// ---------------- software grid barrier (one counter per instance) ----------
__device__ __forceinline__ void gbar(int* cnt, int idx) {
  __syncthreads();
  if (threadIdx.x == 0) {
    __hip_atomic_fetch_add(&cnt[idx], 1, __ATOMIC_RELEASE, __HIP_MEMORY_SCOPE_AGENT);
    while (__hip_atomic_load(&cnt[idx], __ATOMIC_RELAXED, __HIP_MEMORY_SCOPE_AGENT) < GPERS) {
      __builtin_amdgcn_s_sleep(16);
    }
    (void)__hip_atomic_load(&cnt[idx], __ATOMIC_ACQUIRE, __HIP_MEMORY_SCOPE_AGENT);
  }
  __syncthreads();
}

// ---------------- weight prep ----------------
__global__ __launch_bounds__(256) void transpose_bf16_kernel(const float* __restrict__ W,
                                                             __hip_bfloat16* __restrict__ Wt,
                                                             int K, int N, int Npad) {
  __shared__ float t[32][33];
  const int tx = threadIdx.x, ty = threadIdx.y;  // 32 x 8
  const int n0 = blockIdx.x * 32, k0 = blockIdx.y * 32;
#pragma unroll
  for (int i = 0; i < 4; i++) {
    int k = k0 + ty + i * 8;
    t[ty + i * 8][tx] = (k < K && n0 + tx < N) ? W[(size_t)k * N + n0 + tx] : 0.f;
  }
  __syncthreads();
#pragma unroll
  for (int i = 0; i < 4; i++) {
    int n = n0 + ty + i * 8;
    if (n < Npad && k0 + tx < K)
      Wt[(size_t)n * K + k0 + tx] = __float2bfloat16(t[tx][ty + i * 8]);
  }
}

__global__ void conv_bf16_kernel(const float* __restrict__ src, __hip_bfloat16* __restrict__ dst,
                                 int n) {
  int i = blockIdx.x * 256 + threadIdx.x;
  if (i < n) dst[i] = __float2bfloat16(src[i]);
}

__global__ void bqaq_kernel(const float* __restrict__ b_q, const float* __restrict__ b_aq,
                            const __hip_bfloat16* __restrict__ Wt_aq, float* __restrict__ b_qaq) {
  int n = blockIdx.x * 256 + threadIdx.x;
  if (n >= DIN) return;
  const __hip_bfloat16* wr = Wt_aq + (size_t)n * DIN;
  float s = b_aq[n];
  for (int k = 0; k < DIN; k++) s += b_q[k] * __bfloat162float(wr[k]);
  b_qaq[n] = s;
}

// ---------------- big MFMA GEMM (precompute) ----------------
// TRANSC: 0 = row-major C[M,N]; 1 = C^T [N,M]; 2 = attention layout
//         (row=(b,s), col=(h,d) -> C[((b*16+h)*512+s)*64+d])
__device__ inline short8 load_chunk(const __hip_bfloat16* p) {
  return *reinterpret_cast<const short8*>(p);
}
__device__ inline short8 load_chunk(const float* p) {
  short8 r;
#pragma unroll
  for (int j = 0; j < 8; j++) r[j] = f2bs(p[j]);
  return r;
}

template <int TRANSC, typename TA, typename TC>
__global__ __launch_bounds__(256) void gemm_big(const TA* __restrict__ A,
                                                const __hip_bfloat16* __restrict__ Bt,
                                                const float* __restrict__ bias,
                                                TC* __restrict__ C, int M, int N, int K) {
  __shared__ short lsA[128 * 64];
  __shared__ short lsB[128 * 64];
  const int tid = threadIdx.x;
  const int l = tid & 63, w = tid >> 6;
  const int wr = (w >> 1) * 64, wc = (w & 1) * 64;
  const int brow = blockIdx.y * 128, bcol = blockIdx.x * 128;
  f32x4 acc[4][4];
#pragma unroll
  for (int i = 0; i < 4; i++)
#pragma unroll
    for (int j = 0; j < 4; j++)
#pragma unroll
      for (int r = 0; r < 4; r++) acc[i][j][r] = 0.f;

  short8 ra[4], rb[4];
  auto gload = [&](int k0) {
#pragma unroll
    for (int q = 0; q < 4; q++) {
      int i = tid + q * 256;
      int row = i >> 3, c = i & 7;
      ra[q] = load_chunk(A + (size_t)(brow + row) * K + k0 + c * 8);
      rb[q] = load_chunk(Bt + (size_t)(bcol + row) * K + k0 + c * 8);
    }
  };
  auto lwrite = [&]() {
#pragma unroll
    for (int q = 0; q < 4; q++) {
      int i = tid + q * 256;
      int row = i >> 3, c = i & 7;
      int sw = c ^ (row & 7);
      *reinterpret_cast<short8*>(&lsA[row * 64 + sw * 8]) = ra[q];
      *reinterpret_cast<short8*>(&lsB[row * 64 + sw * 8]) = rb[q];
    }
  };
  gload(0);
  for (int k0 = 0; k0 < K; k0 += 64) {
    __syncthreads();
    lwrite();
    if (k0 + 64 < K) gload(k0 + 64);
    __syncthreads();
#pragma unroll
    for (int ks = 0; ks < 2; ks++) {
      short8 af[4], bfv[4];
#pragma unroll
      for (int mi = 0; mi < 4; mi++) {
        int row = wr + mi * 16 + (l & 15);
        int c = ks * 4 + (l >> 4);
        af[mi] = *reinterpret_cast<const short8*>(&lsA[row * 64 + (c ^ (row & 7)) * 8]);
      }
#pragma unroll
      for (int ni = 0; ni < 4; ni++) {
        int row = wc + ni * 16 + (l & 15);
        int c = ks * 4 + (l >> 4);
        bfv[ni] = *reinterpret_cast<const short8*>(&lsB[row * 64 + (c ^ (row & 7)) * 8]);
      }
#pragma unroll
      for (int mi = 0; mi < 4; mi++)
#pragma unroll
        for (int ni = 0; ni < 4; ni++)
          acc[mi][ni] =
              __builtin_amdgcn_mfma_f32_16x16x32_bf16(af[mi], bfv[ni], acc[mi][ni], 0, 0, 0);
    }
  }
#pragma unroll
  for (int mi = 0; mi < 4; mi++)
#pragma unroll
    for (int ni = 0; ni < 4; ni++)
#pragma unroll
      for (int r = 0; r < 4; r++) {
        int row = brow + wr + mi * 16 + (l >> 4) * 4 + r;
        int col = bcol + wc + ni * 16 + (l & 15);
        float v = acc[mi][ni][r];
        if (bias) v += bias[col];
        if (TRANSC == 1) {
          store_f(&C[(size_t)col * M + row], v);
        } else if (TRANSC == 2) {
          int bb = row >> 9, s = row & 511, hh = col >> 6, dd = col & 63;
          store_f(&C[(((size_t)(bb * 16 + hh) * 512) + s) * 64 + dd], v);
        } else {
          store_f(&C[(size_t)row * N + col], v);
        }
      }
}

// ---------------- LayerNorm (precompute: kv) ----------------
template <typename TOUT>
__global__ __launch_bounds__(256) void ln_kernel(const float* __restrict__ x,
                                                 const float* __restrict__ g,
                                                 const float* __restrict__ be,
                                                 TOUT* __restrict__ out, int C,
                                                 size_t row_stride, int col_stride) {
  const int row = blockIdx.x;
  const int tid = threadIdx.x;
  const float* xr = x + (size_t)row * C;
  float s = 0.f, s2 = 0.f;
  for (int c = tid; c < C; c += 256) {
    float v = xr[c];
    s += v;
    s2 += v * v;
  }
  __shared__ float r1[256], r2[256];
  r1[tid] = s;
  r2[tid] = s2;
  __syncthreads();
  for (int st = 128; st > 0; st >>= 1) {
    if (tid < st) {
      r1[tid] += r1[tid + st];
      r2[tid] += r2[tid + st];
    }
    __syncthreads();
  }
  float mean = r1[0] / C;
  float var = r2[0] / C - mean * mean;
  float inv = 1.0f / sqrtf(var + 1e-5f);
  for (int c = tid; c < C; c += 256) {
    float v = (xr[c] - mean) * inv * g[c] + be[c];
    store_f(&out[(size_t)row * row_stride + (size_t)c * col_stride], v);
  }
}

// ---------------- init kernels ----------------
__global__ void init_act_kernel(const float* __restrict__ init_state, float* __restrict__ act) {
  int i = blockIdx.x * 256 + threadIdx.x;
  if (i < B_ * DMODEL) act[i] = init_state[i & (DMODEL - 1)];
}

__global__ void init_hist_kernel(const float* __restrict__ init_hist, float* __restrict__ hist) {
  int i = blockIdx.x * 256 + threadIdx.x;
  if (i >= B_ * DMODEL * DMEM) return;
  int m = i & (DMEM - 1);
  int bd = i >> 5;
  int d = bd & (DMODEL - 1);
  hist[(size_t)bd * HIST_W + m] = init_hist[d * DMEM + m];
}

// also precomputes rA/rO and tick-0 action-sync state
__global__ void init_sync_kernel(const float* __restrict__ init_state,
                                 const float* __restrict__ decay_action,
                                 const float* __restrict__ decay_out,
                                 const int* __restrict__ la, const int* __restrict__ ra,
                                 const int* __restrict__ lo, const int* __restrict__ ro,
                                 float* __restrict__ aA, float* __restrict__ bA,
                                 float* __restrict__ aO, float* __restrict__ bO,
                                 __hip_bfloat16* __restrict__ syncA, float* __restrict__ rAv,
                                 float* __restrict__ rOv) {
  int i = blockIdx.x * 256 + threadIdx.x;
  if (i >= B_ * NSYNC) return;
  int j = i & (NSYNC - 1);
  if (i < NSYNC) {
    rAv[i] = expf(-fminf(fmaxf(decay_action[i], 0.f), 15.f));
    rOv[i] = expf(-fminf(fmaxf(decay_out[i], 0.f), 15.f));
  }
  float pA = init_state[la[j]] * init_state[ra[j]];
  aA[i] = pA;
  bA[i] = 1.f;
  syncA[i] = __float2bfloat16(pA);  // pA / sqrt(1)
  aO[i] = init_state[lo[j]] * init_state[ro[j]];
  bO[i] = 1.f;
}

// ---------------- persistent tick kernel ----------------
struct CArgs {
  const __hip_bfloat16 *Wt_qaq, *Wt_ao, *Wt_s1, *Wt_s2, *Wt_out;
  const __hip_bfloat16 *kh, *vh;  // head-major [b][h][s][d]
  const float *b_qaq, *b_ao, *b_s1, *b_s2, *b_out;
  const float *g_s, *be_s, *g_n, *be_n;
  const float *W_n1, *b_n1, *W_n2, *b_n2;
  const int *la, *ra, *lo, *ro;
  const float *rAv, *rOv;
  float *qhb, *part, *histf, *act, *aA, *bA, *aO, *bO, *nlmraw, *outp;
  __hip_bfloat16 *syncA, *syncO, *attnv, *pre, *h1;
  int* bar;
};

// one 64xN-tile MFMA matmul step: C-tile rows 0..63, cols [bcol,bcol+64), K in [kb,kb+kchunk)
template <typename EPI>
__device__ __forceinline__ void mm_tile64(const __hip_bfloat16* __restrict__ A, int lda,
                                          const __hip_bfloat16* __restrict__ Bt, int ldb,
                                          int bcol, int kb, int kchunk, short* lsA, short* lsB,
                                          EPI epi) {
  const int tid = threadIdx.x;
  const int l = tid & 63, w = tid >> 6;
  f32x4 acc[4];
#pragma unroll
  for (int i = 0; i < 4; i++)
#pragma unroll
    for (int r = 0; r < 4; r++) acc[i][r] = 0.f;
  short8 ra[2], rb[2];
  auto gload = [&](int k0) {
#pragma unroll
    for (int q = 0; q < 2; q++) {
      int i = tid + q * 256;
      int row = i >> 3, c = i & 7;
      ra[q] = *reinterpret_cast<const short8*>(A + (size_t)row * lda + k0 + c * 8);
      rb[q] = *reinterpret_cast<const short8*>(Bt + (size_t)(bcol + row) * ldb + k0 + c * 8);
    }
  };
  auto lwrite = [&]() {
#pragma unroll
    for (int q = 0; q < 2; q++) {
      int i = tid + q * 256;
      int row = i >> 3, c = i & 7;
      int sw = c ^ (row & 7);
      *reinterpret_cast<short8*>(&lsA[row * 64 + sw * 8]) = ra[q];
      *reinterpret_cast<short8*>(&lsB[row * 64 + sw * 8]) = rb[q];
    }
  };
  gload(kb);
  for (int k0 = kb; k0 < kb + kchunk; k0 += 64) {
    __syncthreads();
    lwrite();
    if (k0 + 64 < kb + kchunk) gload(k0 + 64);
    __syncthreads();
#pragma unroll
    for (int ks = 0; ks < 2; ks++) {
      int rowa = w * 16 + (l & 15);
      int c = ks * 4 + (l >> 4);
      short8 af = *reinterpret_cast<const short8*>(&lsA[rowa * 64 + (c ^ (rowa & 7)) * 8]);
#pragma unroll
      for (int ni = 0; ni < 4; ni++) {
        int rowb = ni * 16 + (l & 15);
        short8 bfv = *reinterpret_cast<const short8*>(&lsB[rowb * 64 + (c ^ (rowb & 7)) * 8]);
        acc[ni] = __builtin_amdgcn_mfma_f32_16x16x32_bf16(af, bfv, acc[ni], 0, 0, 0);
      }
    }
  }
#pragma unroll
  for (int ni = 0; ni < 4; ni++)
#pragma unroll
    for (int r = 0; r < 4; r++) {
      int m = w * 16 + (l >> 4) * 4 + r;
      int n = bcol + ni * 16 + (l & 15);
      epi(m, n, acc[ni][r]);
    }
}

__global__ __launch_bounds__(256) void ctm_coop(CArgs a) {
  __shared__ __align__(16) char smem[17408];
  short* lsA = (short*)smem;
  short* lsB = (short*)(smem + 8192);
  float* sf = (float*)smem;
  const int tid = threadIdx.x;
  const int gbx = blockIdx.x;
  const int G = GPERS;
  int bi = 0;  // barrier instance index (same sequence on all blocks)

  for (int t = 0; t < TICKS; ++t) {
    // ---- P1: qh = syncA @ (W_q W_aq) + b_qaq ; pack act -> pre[:,1024:] ----
    for (int u = gbx; u < 16; u += G)
      mm_tile64(a.syncA, NSYNC, a.Wt_qaq, NSYNC, u * 64, 0, NSYNC, lsA, lsB,
                [&](int m, int n, float v) { a.qhb[m * DIN + n] = v + a.b_qaq[n]; });
    if (gbx >= 16) {
      int stride = (G - 16) * 256;
      for (int i = (gbx - 16) * 256 + tid; i < B_ * DMODEL; i += stride) {
        int b = i >> 11, j = i & (DMODEL - 1);
        a.pre[(size_t)b * 3072 + DIN + j] = __float2bfloat16(a.act[i]);
      }
    }
    gbar(a.bar, bi++);
    // ---- P2: attention (head-major K/V, coalesced streaming) ----
    for (int u = gbx; u < B_ * NH; u += G) {
      const int b = u >> 4, h = u & (NH - 1);
      const __hip_bfloat16* Kp = a.kh + (size_t)u * (S_ * DH);
      const __hip_bfloat16* Vp = a.vh + (size_t)u * (S_ * DH);
      float* qs = sf;            // 64 f
      float* wv = sf + 64;       // 512 f
      float* red = sf + 576;     // 256 f
      float* red2 = sf + 1024;   // 2048 f  (ends at 3072 f = 12 KB)
      if (tid < DH) qs[tid] = a.qhb[b * DIN + h * DH + tid];
      __syncthreads();
      float sc[2];
#pragma unroll
      for (int r = 0; r < 2; ++r) {
        int s = tid + r * 256;
        const short8* kp = reinterpret_cast<const short8*>(Kp + (size_t)s * DH);
        float accv = 0.f;
#pragma unroll
        for (int q = 0; q < 8; ++q) {
          short8 kk = kp[q];
#pragma unroll
          for (int j = 0; j < 8; ++j) accv += qs[q * 8 + j] * bfs(kk[j]);
        }
        sc[r] = accv * 0.125f;
      }
      red[tid] = fmaxf(sc[0], sc[1]);
      __syncthreads();
      for (int st = 128; st > 0; st >>= 1) {
        if (tid < st) red[tid] = fmaxf(red[tid], red[tid + st]);
        __syncthreads();
      }
      const float mx = red[0];
      __syncthreads();
      float e0 = expf(sc[0] - mx), e1 = expf(sc[1] - mx);
      wv[tid] = e0;
      wv[tid + 256] = e1;
      red[tid] = e0 + e1;
      __syncthreads();
      for (int st = 128; st > 0; st >>= 1) {
        if (tid < st) red[tid] += red[tid + st];
        __syncthreads();
      }
      const float invZ = 1.f / red[0];
      __syncthreads();
      // PV: thread t -> d-chunk d8 = t&7 (8 bf16), s-group sg = t>>3 (32 groups)
      const int d8 = tid & 7, sg = tid >> 3;
      float pacc[8];
#pragma unroll
      for (int j = 0; j < 8; ++j) pacc[j] = 0.f;
      for (int s = sg; s < S_; s += 32) {
        float wgt = wv[s];
        short8 vv = *reinterpret_cast<const short8*>(Vp + (size_t)s * DH + d8 * 8);
#pragma unroll
        for (int j = 0; j < 8; ++j) pacc[j] += wgt * bfs(vv[j]);
      }
#pragma unroll
      for (int j = 0; j < 8; ++j) red2[sg * 64 + d8 * 8 + j] = pacc[j];
      __syncthreads();
      if (tid < DH) {
        float r = 0.f;
#pragma unroll
        for (int g2 = 0; g2 < 32; ++g2) r += red2[g2 * 64 + tid];
        a.attnv[b * DIN + h * DH + tid] = __float2bfloat16(r * invZ);
      }
      __syncthreads();
    }
    gbar(a.bar, bi++);
    // ---- P3: ao GEMM -> pre[:, :1024] ----
    for (int u = gbx; u < 16; u += G)
      mm_tile64(a.attnv, DIN, a.Wt_ao, DIN, u * 64, 0, DIN, lsA, lsB, [&](int m, int n, float v) {
        a.pre[(size_t)m * 3072 + n] = __float2bfloat16(v + a.b_ao[n]);
      });
    gbar(a.bar, bi++);
    // ---- P4: s1 GEMM split-K8 ----
    for (int u = gbx; u < 256; u += G) {
      int nt = u & 31, ks = u >> 5;
      mm_tile64(a.pre, 3072, a.Wt_s1, 3072, nt * 64, ks * 384, 384, lsA, lsB,
                [&](int m, int n, float v) { a.part[((size_t)ks * 64 + m) * DMODEL + n] = v; });
    }
    gbar(a.bar, bi++);
    // ---- P5: s1 reduce + gelu -> h1 ----
    for (int u = gbx; u < 64; u += G) {
      for (int i = 0; i < 8; i++) {
        int n = tid + i * 256;
        float s = a.b_s1[n];
        for (int ks = 0; ks < 8; ks++) s += a.part[((size_t)ks * 64 + u) * DMODEL + n];
        a.h1[(size_t)u * DMODEL + n] = __float2bfloat16(gelu_f(s));
      }
    }
    gbar(a.bar, bi++);
    // ---- P6: s2 GEMM split-K8 ----
    for (int u = gbx; u < 256; u += G) {
      int nt = u & 31, ks = u >> 5;
      mm_tile64(a.h1, DMODEL, a.Wt_s2, DMODEL, nt * 64, ks * 256, 256, lsA, lsB,
                [&](int m, int n, float v) { a.part[((size_t)ks * 64 + m) * DMODEL + n] = v; });
    }
    gbar(a.bar, bi++);
    // ---- P7: s2 reduce + LN -> hist slot 32+t ----
    for (int u = gbx; u < 64; u += G) {
      float v[8];
      float s = 0.f, s2 = 0.f;
      for (int i = 0; i < 8; i++) {
        int n = tid + i * 256;
        float x = a.b_s2[n];
        for (int ks = 0; ks < 8; ks++) x += a.part[((size_t)ks * 64 + u) * DMODEL + n];
        v[i] = x;
        s += x;
        s2 += x * x;
      }
      float* r1 = sf;
      float* r2 = sf + 256;
      r1[tid] = s;
      r2[tid] = s2;
      __syncthreads();
      for (int st = 128; st > 0; st >>= 1) {
        if (tid < st) {
          r1[tid] += r1[tid + st];
          r2[tid] += r2[tid + st];
        }
        __syncthreads();
      }
      float mean = r1[0] / DMODEL;
      float var = r2[0] / DMODEL - mean * mean;
      float inv = 1.f / sqrtf(var + 1e-5f);
      __syncthreads();
      for (int i = 0; i < 8; i++) {
        int n = tid + i * 256;
        float pa = (v[i] - mean) * inv * a.g_s[n] + a.be_s[n];
        a.histf[((size_t)u * DMODEL + n) * HIST_W + 32 + t] = pa;
      }
      __syncthreads();
    }
    gbar(a.bar, bi++);
    // ---- P8: NLM ----
    for (int u = gbx; u < 512; u += G) {
      float* w1s = sf;         // 4096 f
      float* b1s = sf + 4096;  // 128 f
      int d0 = u * 4;
      for (int i = tid; i < 4096; i += 256) w1s[i] = a.W_n1[(size_t)d0 * 1024 + i];
      if (tid < 128) b1s[tid] = a.b_n1[d0 * 32 + tid];
      __syncthreads();
      int b = tid & 63, dsub = tid >> 6;
      int d = d0 + dsub;
      const float* hw = a.histf + ((size_t)(b * DMODEL + d)) * HIST_W + t + 1;
      float win[DMEM];
#pragma unroll
      for (int m = 0; m < DMEM; ++m) win[m] = hw[m];
      const float* w1 = w1s + dsub * 1024;
      const float* bb = b1s + dsub * 32;
      const float* w2 = a.W_n2 + d * HNLM;
      float acc = 0.f;
      for (int h = 0; h < HNLM; ++h) {
        float s = bb[h];
#pragma unroll
        for (int m = 0; m < DMEM; ++m) s += win[m] * w1[m * HNLM + h];
        acc += fmaxf(s, 0.f) * w2[h];
      }
      a.nlmraw[(size_t)b * DMODEL + d] = acc + a.b_n2[d];
      __syncthreads();
    }
    gbar(a.bar, bi++);
    // ---- P9: LN(nlmraw) -> act ; syncA(t+1), syncO(t) ----
    for (int u = gbx; u < 64; u += G) {
      const float* xr = a.nlmraw + (size_t)u * DMODEL;
      float* arow = sf;         // 2048 f
      float* r1 = sf + 2048;    // 256 f
      float* r2 = sf + 2304;    // 256 f
      float xv[8];
      float s = 0.f, s2 = 0.f;
      for (int i = 0; i < 8; i++) {
        float x = xr[tid + i * 256];
        xv[i] = x;
        s += x;
        s2 += x * x;
      }
      r1[tid] = s;
      r2[tid] = s2;
      __syncthreads();
      for (int st = 128; st > 0; st >>= 1) {
        if (tid < st) {
          r1[tid] += r1[tid + st];
          r2[tid] += r2[tid + st];
        }
        __syncthreads();
      }
      float mean = r1[0] / DMODEL;
      float var = r2[0] / DMODEL - mean * mean;
      float inv = 1.f / sqrtf(var + 1e-5f);
      __syncthreads();
      for (int i = 0; i < 8; i++) {
        int n = tid + i * 256;
        float av = (xv[i] - mean) * inv * a.g_n[n] + a.be_n[n];
        a.act[(size_t)u * DMODEL + n] = av;
        arow[n] = av;
      }
      __syncthreads();
      for (int j = tid; j < NSYNC; j += 256) {
        size_t idx = (size_t)u * NSYNC + j;
        float pA = arow[a.la[j]] * arow[a.ra[j]];
        float r = a.rAv[j];
        float av2 = r * a.aA[idx] + pA, bv2 = r * a.bA[idx] + 1.f;
        a.aA[idx] = av2;
        a.bA[idx] = bv2;
        a.syncA[idx] = __float2bfloat16(av2 / sqrtf(bv2));
        float pO = arow[a.lo[j]] * arow[a.ro[j]];
        float ro = a.rOv[j];
        av2 = ro * a.aO[idx] + pO;
        bv2 = ro * a.bO[idx] + 1.f;
        a.aO[idx] = av2;
        a.bO[idx] = bv2;
        a.syncO[idx] = __float2bfloat16(av2 / sqrtf(bv2));
      }
      __syncthreads();
    }
    // NOTE: no barrier between P9 and P10 — P10 task u (=b) consumes only
    // syncO row u, produced by the SAME block (u = gbx in both loops).
    // ---- P10: output head (GEMV + entropy) ----
    for (int u = gbx; u < 64; u += G) {
      float* so = sf;          // 512 f
      float* pv = sf + 512;    // 1024 f
      float* red = sf + 1536;  // 256 f
      __syncthreads();
      so[tid] = __bfloat162float(a.syncO[(size_t)u * NSYNC + tid]);
      so[tid + 256] = __bfloat162float(a.syncO[(size_t)u * NSYNC + 256 + tid]);
      __syncthreads();
      float pr[4];
#pragma unroll
      for (int i = 0; i < 4; i++) {
        int n = tid + i * 256;
        pr[i] = 0.f;
        if (n < DOUT) {
          const unsigned* wr = reinterpret_cast<const unsigned*>(a.Wt_out + (size_t)n * NSYNC);
          float sacc = a.b_out[n];
          for (int c = 0; c < 256; c++) {
            unsigned uu = wr[c];
            sacc += so[2 * c] * bf_lo(uu) + so[2 * c + 1] * bf_hi(uu);
          }
          pr[i] = sacc;
          pv[n] = sacc;
        }
      }
      __syncthreads();
      float m = -1e30f;
      for (int o = tid; o < DOUT; o += 256) m = fmaxf(m, pv[o]);
      red[tid] = m;
      __syncthreads();
      for (int st = 128; st > 0; st >>= 1) {
        if (tid < st) red[tid] = fmaxf(red[tid], red[tid + st]);
        __syncthreads();
      }
      m = red[0];
      __syncthreads();
      float z = 0.f, s1 = 0.f;
      for (int o = tid; o < DOUT; o += 256) {
        float wv2 = pv[o] - m;
        float e = expf(wv2);
        z += e;
        s1 += e * wv2;
      }
      red[tid] = z;
      __syncthreads();
      for (int st = 128; st > 0; st >>= 1) {
        if (tid < st) red[tid] += red[tid + st];
        __syncthreads();
      }
      const float Z = red[0];
      __syncthreads();
      red[tid] = s1;
      __syncthreads();
      for (int st = 128; st > 0; st >>= 1) {
        if (tid < st) red[tid] += red[tid + st];
        __syncthreads();
      }
      const float S1 = red[0];
      const float ne = -(S1 / Z - logf(Z)) / 6.907755278982137f;
#pragma unroll
      for (int i = 0; i < 4; i++) {
        int n = tid + i * 256;
        if (n < DOUT) a.outp[((size_t)u * DOUT + n) * TICKS + t] = pr[i];
      }
      if (tid == 0) {
        float* c = a.outp + (size_t)B_ * DOUT * TICKS;
        c[u * 2 * TICKS + t] = ne;
        c[u * 2 * TICKS + TICKS + t] = 1.f - ne;
      }
      __syncthreads();
    }
    gbar(a.bar, bi++);
  }
}

// ---------------------------------------------------------------------------
extern "C" void kernel_launch(void* const* d_in, const int* in_sizes, int n_in,
                              void* d_out, int out_size, void* d_ws, size_t ws_size,
                              hipStream_t stream) {
  const float* x = (const float*)d_in[0];
  const float* W_kv = (const float*)d_in[1];
  const float* b_kv = (const float*)d_in[2];
  const float* g_kv = (const float*)d_in[3];
  const float* be_kv = (const float*)d_in[4];
  const float* W_q = (const float*)d_in[5];
  const float* b_q = (const float*)d_in[6];
  const float* W_aq = (const float*)d_in[7];
  const float* b_aq = (const float*)d_in[8];
  const float* W_ak = (const float*)d_in[9];
  const float* b_ak = (const float*)d_in[10];
  const float* W_av = (const float*)d_in[11];
  const float* b_av = (const float*)d_in[12];
  const float* W_ao = (const float*)d_in[13];
  const float* b_ao = (const float*)d_in[14];
  const float* W_s1 = (const float*)d_in[15];
  const float* b_s1 = (const float*)d_in[16];
  const float* W_s2 = (const float*)d_in[17];
  const float* b_s2 = (const float*)d_in[18];
  const float* g_s = (const float*)d_in[19];
  const float* be_s = (const float*)d_in[20];
  const float* W_n1 = (const float*)d_in[21];
  const float* b_n1 = (const float*)d_in[22];
  const float* W_n2 = (const float*)d_in[23];
  const float* b_n2 = (const float*)d_in[24];
  const float* g_n = (const float*)d_in[25];
  const float* be_n = (const float*)d_in[26];
  const float* init_state = (const float*)d_in[27];
  const float* init_hist = (const float*)d_in[28];
  const float* decay_action = (const float*)d_in[29];
  const float* decay_out = (const float*)d_in[30];
  const float* W_out = (const float*)d_in[31];
  const float* b_out = (const float*)d_in[32];
  const int* idx_la = (const int*)d_in[33];
  const int* idx_ra = (const int*)d_in[34];
  const int* idx_lo = (const int*)d_in[35];
  const int* idx_ro = (const int*)d_in[36];
  float* out = (float*)d_out;

  // ---- workspace carve ----
  char* wsb = (char*)d_ws;
  size_t off = 0;
  auto alloc = [&](size_t bytes) -> char* {
    char* p = wsb + off;
    off += (bytes + 255) & ~(size_t)255;
    return p;
  };
  const size_t MS = (size_t)B_ * S_;  // 32768
  char* regionA = alloc(MS * DIN * 4);  // kvraw fp32; later kh+vh bf16 (head-major)
  __hip_bfloat16* kv = (__hip_bfloat16*)alloc(MS * DIN * 2);
  float* histf = (float*)alloc((size_t)B_ * DMODEL * HIST_W * 4);
  __hip_bfloat16* Wt_kv = (__hip_bfloat16*)alloc((size_t)DIN * F_ * 2);
  __hip_bfloat16* Wt_ak = (__hip_bfloat16*)alloc((size_t)DIN * DIN * 2);
  __hip_bfloat16* Wt_av = (__hip_bfloat16*)alloc((size_t)DIN * DIN * 2);
  __hip_bfloat16* Wt_aq = (__hip_bfloat16*)alloc((size_t)DIN * DIN * 2);
  __hip_bfloat16* Wt_ao = (__hip_bfloat16*)alloc((size_t)DIN * DIN * 2);
  __hip_bfloat16* W_qb = (__hip_bfloat16*)alloc((size_t)NSYNC * DIN * 2);
  __hip_bfloat16* Wt_qaq = (__hip_bfloat16*)alloc((size_t)DIN * NSYNC * 2);
  __hip_bfloat16* Wt_s1 = (__hip_bfloat16*)alloc((size_t)DMODEL * (DIN + DMODEL) * 2);
  __hip_bfloat16* Wt_s2 = (__hip_bfloat16*)alloc((size_t)DMODEL * DMODEL * 2);
  __hip_bfloat16* Wt_out = (__hip_bfloat16*)alloc((size_t)DOUT * NSYNC * 2);
  float* b_qaq = (float*)alloc(DIN * 4);
  float* partial = (float*)alloc((size_t)8 * 64 * DMODEL * 4);
  float* act = (float*)alloc((size_t)B_ * DMODEL * 4);
  float* aA = (float*)alloc((size_t)B_ * NSYNC * 4);
  float* bA = (float*)alloc((size_t)B_ * NSYNC * 4);
  float* aO = (float*)alloc((size_t)B_ * NSYNC * 4);
  float* bO = (float*)alloc((size_t)B_ * NSYNC * 4);
  __hip_bfloat16* syncA = (__hip_bfloat16*)alloc((size_t)B_ * NSYNC * 2);
  __hip_bfloat16* syncO = (__hip_bfloat16*)alloc((size_t)B_ * NSYNC * 2);
  float* qhb = (float*)alloc((size_t)B_ * DIN * 4);
  __hip_bfloat16* attnv = (__hip_bfloat16*)alloc((size_t)B_ * DIN * 2);
  __hip_bfloat16* pre = (__hip_bfloat16*)alloc((size_t)B_ * (DIN + DMODEL) * 2);
  __hip_bfloat16* h1 = (__hip_bfloat16*)alloc((size_t)B_ * DMODEL * 2);
  float* nlmraw = (float*)alloc((size_t)B_ * DMODEL * 4);
  float* rAv = (float*)alloc(NSYNC * 4);
  float* rOv = (float*)alloc(NSYNC * 4);
  int* gbarrier = (int*)alloc(1024);  // 160 barrier slots (128 used)

  float* kvraw = (float*)regionA;
  __hip_bfloat16* kh = (__hip_bfloat16*)regionA;                      // [b][h][s][d]
  __hip_bfloat16* vh = (__hip_bfloat16*)(regionA + MS * DIN * 2);     // [b][h][s][d]

  // zero barrier counters (async, captured in graph -> replays deterministically)
  hipMemsetAsync(gbarrier, 0, 1024, stream);

  dim3 t32x8(32, 8);
  // ---- weight prep ----
  transpose_bf16_kernel<<<dim3(F_ / 32, DIN / 32), t32x8, 0, stream>>>(W_kv, Wt_kv, F_, DIN, DIN);
  transpose_bf16_kernel<<<dim3(DIN / 32, DIN / 32), t32x8, 0, stream>>>(W_ak, Wt_ak, DIN, DIN, DIN);
  transpose_bf16_kernel<<<dim3(DIN / 32, DIN / 32), t32x8, 0, stream>>>(W_av, Wt_av, DIN, DIN, DIN);
  transpose_bf16_kernel<<<dim3(DIN / 32, DIN / 32), t32x8, 0, stream>>>(W_aq, Wt_aq, DIN, DIN, DIN);
  transpose_bf16_kernel<<<dim3(DIN / 32, DIN / 32), t32x8, 0, stream>>>(W_ao, Wt_ao, DIN, DIN, DIN);
  transpose_bf16_kernel<<<dim3(DMODEL / 32, (DIN + DMODEL) / 32), t32x8, 0, stream>>>(
      W_s1, Wt_s1, DIN + DMODEL, DMODEL, DMODEL);
  transpose_bf16_kernel<<<dim3(DMODEL / 32, DMODEL / 32), t32x8, 0, stream>>>(W_s2, Wt_s2, DMODEL,
                                                                              DMODEL, DMODEL);
  transpose_bf16_kernel<<<dim3((DOUT + 31) / 32, NSYNC / 32), t32x8, 0, stream>>>(
      W_out, Wt_out, NSYNC, DOUT, DOUT);
  conv_bf16_kernel<<<(NSYNC * DIN + 255) / 256, 256, 0, stream>>>(W_q, W_qb, NSYNC * DIN);
  bqaq_kernel<<<4, 256, 0, stream>>>(b_q, b_aq, Wt_aq, b_qaq);

  // ---- precompute ----
  gemm_big<0, float, float><<<dim3(DIN / 128, MS / 128), 256, 0, stream>>>(x, Wt_kv, b_kv, kvraw,
                                                                           (int)MS, DIN, F_);
  ln_kernel<__hip_bfloat16><<<(int)MS, 256, 0, stream>>>(kvraw, g_kv, be_kv, kv, DIN, DIN, 1);
  gemm_big<2, __hip_bfloat16, __hip_bfloat16><<<dim3(DIN / 128, MS / 128), 256, 0, stream>>>(
      kv, Wt_ak, b_ak, kh, (int)MS, DIN, DIN);
  gemm_big<2, __hip_bfloat16, __hip_bfloat16><<<dim3(DIN / 128, MS / 128), 256, 0, stream>>>(
      kv, Wt_av, b_av, vh, (int)MS, DIN, DIN);
  gemm_big<1, __hip_bfloat16, __hip_bfloat16><<<dim3(DIN / 128, NSYNC / 128), 256, 0, stream>>>(
      W_qb, Wt_aq, nullptr, Wt_qaq, NSYNC, DIN, DIN);

  // ---- state init ----
  init_act_kernel<<<(B_ * DMODEL + 255) / 256, 256, 0, stream>>>(init_state, act);
  init_hist_kernel<<<(B_ * DMODEL * DMEM + 255) / 256, 256, 0, stream>>>(init_hist, histf);
  init_sync_kernel<<<(B_ * NSYNC + 255) / 256, 256, 0, stream>>>(
      init_state, decay_action, decay_out, idx_la, idx_ra, idx_lo, idx_ro, aA, bA, aO, bO, syncA,
      rAv, rOv);

  // ---- persistent tick loop (regular launch; 256 blocks <= 1/CU) ----
  CArgs ca;
  ca.Wt_qaq = Wt_qaq; ca.Wt_ao = Wt_ao; ca.Wt_s1 = Wt_s1; ca.Wt_s2 = Wt_s2; ca.Wt_out = Wt_out;
  ca.kh = kh; ca.vh = vh;
  ca.b_qaq = b_qaq; ca.b_ao = b_ao; ca.b_s1 = b_s1; ca.b_s2 = b_s2; ca.b_out = b_out;
  ca.g_s = g_s; ca.be_s = be_s; ca.g_n = g_n; ca.be_n = be_n;
  ca.W_n1 = W_n1; ca.b_n1 = b_n1; ca.W_n2 = W_n2; ca.b_n2 = b_n2;
  ca.la = idx_la; ca.ra = idx_ra; ca.lo = idx_lo; ca.ro = idx_ro;
  ca.rAv = rAv; ca.rOv = rOv;
  ca.qhb = qhb; ca.part = partial; ca.histf = histf; ca.act = act;
  ca.aA = aA; ca.bA = bA; ca.aO = aO; ca.bO = bO;
  ca.nlmraw = nlmraw; ca.outp = out;
  ca.syncA = syncA; ca.syncO = syncO; ca.attnv = attnv; ca.pre = pre; ca.h1 = h1;
  ca.bar = gbarrier;

  ctm_coop<<<GPERS, 256, 0, stream>>>(ca);

  (void)in_sizes; (void)n_in; (void)out_size; (void)ws_size;
}